// Round 1
// baseline (229.151 us; speedup 1.0000x reference)
//
#include <hip/hip_runtime.h>
#include <hip/hip_bf16.h>

typedef __attribute__((ext_vector_type(8))) short short8;
typedef __attribute__((ext_vector_type(4))) float f32x4;

#define MFMA16 __builtin_amdgcn_mfma_f32_16x16x32_bf16

__device__ inline unsigned short f2bf(float f) {
  __hip_bfloat16 h = __float2bfloat16(f);
  unsigned short u;
  __builtin_memcpy(&u, &h, 2);
  return u;
}

__device__ inline void storeC(unsigned short* p, float v) { *p = f2bf(v); }
__device__ inline void storeC(float* p, float v) { *p = v; }

__device__ inline void gload16(const void* g, void* l) {
  __builtin_amdgcn_global_load_lds(
      (const __attribute__((address_space(1))) unsigned int*)g,
      (__attribute__((address_space(3))) unsigned int*)l,
      16, 0, 0);
}

// ---------------------------------------------------------------------------
// Weight prep: dst[n][d] = sum_g Wq[d][n + g*512], bf16 out. 512x2048 output.
// grid(8, 32), block 256.
__global__ __launch_bounds__(256)
void wqsum_t(const float* __restrict__ wq, unsigned short* __restrict__ dst) {
  __shared__ float t[64][65];
  const int n0 = blockIdx.x * 64, d0 = blockIdx.y * 64;
  const int tid = threadIdx.x;
#pragma unroll
  for (int it = 0; it < 16; ++it) {
    const int idx = it * 256 + tid;
    const int dd = idx >> 6, nn = idx & 63;
    const float* p = wq + (size_t)(d0 + dd) * 2048 + n0 + nn;
    t[dd][nn] = p[0] + p[512] + p[1024] + p[1536];
  }
  __syncthreads();
#pragma unroll
  for (int it = 0; it < 16; ++it) {
    const int idx = it * 256 + tid;
    const int nn = idx >> 6, dd = idx & 63;
    dst[(size_t)(n0 + nn) * 2048 + d0 + dd] = f2bf(t[dd][nn]);
  }
}

// Generic transpose+convert: dst[c][r] = src[r][c], src is R x C f32.
// grid(C/64, R/64), block 256.
__global__ __launch_bounds__(256)
void transpose_w(const float* __restrict__ src, unsigned short* __restrict__ dst,
                 int R, int C) {
  __shared__ float t[64][65];
  const int c0 = blockIdx.x * 64, r0 = blockIdx.y * 64;
  const int tid = threadIdx.x;
#pragma unroll
  for (int it = 0; it < 16; ++it) {
    const int idx = it * 256 + tid;
    const int r = idx >> 6, c = idx & 63;
    t[r][c] = src[(size_t)(r0 + r) * C + c0 + c];
  }
  __syncthreads();
#pragma unroll
  for (int it = 0; it < 16; ++it) {
    const int idx = it * 256 + tid;
    const int rr = idx >> 6, cc = idx & 63;
    dst[(size_t)(c0 + rr) * R + r0 + cc] = f2bf(t[cc][rr]);
  }
}

// ---------------------------------------------------------------------------
// GEMM C[M,N] = A[M,K] * Bt[N,K]^T. 128x128 tile, BK=64, 4 waves.
// AF32: A is f32 in global, converted to bf16 during reg-staged LDS write.
// else: A is bf16, staged via global_load_lds.
// grid(N/128, M/128, batches). A selected per-z from A0/A1/A2.
template <bool AF32, typename CT>
__global__ __launch_bounds__(256)
void gemm_bt(const void* A0, const void* A1, const void* A2,
             const unsigned short* __restrict__ Bt, CT* __restrict__ C,
             int K, int N, size_t sB, size_t sC) {
  __shared__ unsigned short As[128 * 64];
  __shared__ unsigned short Bs[128 * 64];

  const int tid = threadIdx.x;
  const int lane = tid & 63;
  const int wv = tid >> 6;
  const int wm = (wv >> 1) << 6;
  const int wn = (wv & 1) << 6;
  const int z = blockIdx.z;
  const int m0 = blockIdx.y * 128;
  const int n0 = blockIdx.x * 128;

  const void* Az = (z == 0) ? A0 : (z == 1) ? A1 : A2;
  const unsigned short* Ab = (const unsigned short*)Az;
  const float* Af = (const float*)Az;
  const unsigned short* Bz = Bt + sB * (size_t)z;

  const f32x4 zero = {0.f, 0.f, 0.f, 0.f};
  f32x4 acc[4][4];
#pragma unroll
  for (int i = 0; i < 4; ++i)
#pragma unroll
    for (int j = 0; j < 4; ++j) acc[i][j] = zero;

  const int srow = tid >> 3;        // 0..31 (+32 per issue)
  const int scol = (tid & 7) << 3;  // element col, 0..56 step 8

  for (int k0 = 0; k0 < K; k0 += 64) {
#pragma unroll
    for (int s = 0; s < 4; ++s) {
      const unsigned short* bsrc = Bz + (size_t)(n0 + srow + s * 32) * K + k0 + scol;
      gload16(bsrc, (char*)Bs + tid * 16 + s * 4096);
    }
    if constexpr (AF32) {
#pragma unroll
      for (int s = 0; s < 4; ++s) {
        const float* asrc = Af + (size_t)(m0 + srow + s * 32) * K + k0 + scol;
        const float4 v0 = *(const float4*)(asrc);
        const float4 v1 = *(const float4*)(asrc + 4);
        short8 o;
        o[0] = (short)f2bf(v0.x); o[1] = (short)f2bf(v0.y);
        o[2] = (short)f2bf(v0.z); o[3] = (short)f2bf(v0.w);
        o[4] = (short)f2bf(v1.x); o[5] = (short)f2bf(v1.y);
        o[6] = (short)f2bf(v1.z); o[7] = (short)f2bf(v1.w);
        *(short8*)((char*)As + tid * 16 + s * 4096) = o;
      }
    } else {
#pragma unroll
      for (int s = 0; s < 4; ++s) {
        const unsigned short* asrc = Ab + (size_t)(m0 + srow + s * 32) * K + k0 + scol;
        gload16(asrc, (char*)As + tid * 16 + s * 4096);
      }
    }
    __syncthreads();
#pragma unroll
    for (int kk = 0; kk < 2; ++kk) {
      const int kb = kk * 64 + ((lane >> 4) << 4);  // byte offset within row
      short8 a[4], b[4];
#pragma unroll
      for (int i = 0; i < 4; ++i)
        a[i] = *(const short8*)((const char*)As + (wm + i * 16 + (lane & 15)) * 128 + kb);
#pragma unroll
      for (int j = 0; j < 4; ++j)
        b[j] = *(const short8*)((const char*)Bs + (wn + j * 16 + (lane & 15)) * 128 + kb);
#pragma unroll
      for (int i = 0; i < 4; ++i)
#pragma unroll
        for (int j = 0; j < 4; ++j)
          acc[i][j] = MFMA16(a[i], b[j], acc[i][j], 0, 0, 0);
    }
    __syncthreads();
  }

  CT* Cz = C + sC * (size_t)z;
#pragma unroll
  for (int i = 0; i < 4; ++i) {
    const int row0 = m0 + wm + i * 16 + ((lane >> 4) << 2);
#pragma unroll
    for (int j = 0; j < 4; ++j) {
      const int col = n0 + wn + j * 16 + (lane & 15);
#pragma unroll
      for (int r = 0; r < 4; ++r)
        storeC(&Cz[(size_t)(row0 + r) * N + col], acc[i][j][r]);
    }
  }
}

// ---------------------------------------------------------------------------
// Flash attention (causal), qh/kh/vh/Oh are [4096][512] bf16 (row = b*2048+s,
// col = h*128 + d). Block = 4 waves, each wave owns 16 q-rows; KV tile = 32.
// grid(32 qtiles, 4 heads, 2 batch).
__global__ __launch_bounds__(256)
void attn_fwd(const unsigned short* __restrict__ qh,
              const unsigned short* __restrict__ kh,
              const unsigned short* __restrict__ vh,
              unsigned short* __restrict__ Oh) {
  __shared__ unsigned short K_lds[32 * 128];   // swizzled rows of 256B
  __shared__ unsigned short Vt_lds[128 * 40];  // V transposed, stride 40 elems
  __shared__ unsigned short P_lds[4 * 16 * 40];

  const int tid = threadIdx.x;
  const int lane = tid & 63;
  const int wave = tid >> 6;
  const int qt = blockIdx.x;
  const int h = blockIdx.y;
  const int bi = blockIdx.z;
  const int brow = bi * 2048;
  const int q0 = qt * 64;
  const int qrow_w = q0 + wave * 16;
  const float SCALE = 0.08838834764831845f;  // 1/sqrt(128)

  // Q fragments (held in registers for the whole KV loop)
  short8 qf[4];
  {
    const unsigned short* qp = qh + (size_t)(brow + qrow_w + (lane & 15)) * 512 +
                               h * 128 + ((lane >> 4) << 3);
#pragma unroll
    for (int kk = 0; kk < 4; ++kk) qf[kk] = *(const short8*)(qp + kk * 32);
  }

  const f32x4 zero = {0.f, 0.f, 0.f, 0.f};
  f32x4 o_acc[8];
#pragma unroll
  for (int i = 0; i < 8; ++i) o_acc[i] = zero;
  float m_run[4], l_run[4];
#pragma unroll
  for (int r = 0; r < 4; ++r) { m_run[r] = -1e30f; l_run[r] = 0.f; }

  const int nt = 2 * qt + 2;
  for (int t = 0; t < nt; ++t) {
    const int kbase = t * 32;
    // ---- stage K tile: linear LDS dest, swizzled GLOBAL source ----
#pragma unroll
    for (int s = 0; s < 2; ++s) {
      const int flat = s * 4096 + tid * 16;
      const int r = flat >> 8;
      const int coff = flat & 255;
      const int scoff = coff ^ ((r & 7) << 4);
      const char* src = (const char*)kh +
          ((size_t)(brow + kbase + r) * 512 + h * 128) * 2 + scoff;
      gload16(src, (char*)K_lds + flat);
    }
    // ---- stage V transposed (reg-staged) ----
    {
      const int kk = tid & 31;
      const int dv0 = (tid >> 5) << 4;
      const unsigned short* vsrc =
          vh + (size_t)(brow + kbase + kk) * 512 + h * 128 + dv0;
      const short8 va = *(const short8*)(vsrc);
      const short8 vb = *(const short8*)(vsrc + 8);
#pragma unroll
      for (int j = 0; j < 8; ++j) {
        Vt_lds[(dv0 + j) * 40 + kk] = (unsigned short)va[j];
        Vt_lds[(dv0 + 8 + j) * 40 + kk] = (unsigned short)vb[j];
      }
    }
    __syncthreads();

    // ---- S = Q K^T (two 16x16 n-subtiles) ----
    f32x4 sa[2];
    sa[0] = zero; sa[1] = zero;
#pragma unroll
    for (int n = 0; n < 2; ++n) {
      const int r = n * 16 + (lane & 15);
      const int swz = (r & 7) << 4;
#pragma unroll
      for (int kk = 0; kk < 4; ++kk) {
        const short8 kf = *(const short8*)((const char*)K_lds + r * 256 +
                            ((kk * 64 + ((lane >> 4) << 4)) ^ swz));
        sa[n] = MFMA16(qf[kk], kf, sa[n], 0, 0, 0);
      }
    }

    // ---- online softmax ----
    float p[2][4];
    const int kc = kbase + (lane & 15);
    const int qr = qrow_w + ((lane >> 4) << 2);
#pragma unroll
    for (int n = 0; n < 2; ++n)
#pragma unroll
      for (int r = 0; r < 4; ++r) {
        float v = sa[n][r] * SCALE;
        if (kc + n * 16 > qr + r) v = -1e30f;  // causal mask
        p[n][r] = v;
      }
    float alpha[4];
#pragma unroll
    for (int r = 0; r < 4; ++r) {
      float tmax = fmaxf(p[0][r], p[1][r]);
#pragma unroll
      for (int o = 1; o <= 8; o <<= 1) tmax = fmaxf(tmax, __shfl_xor(tmax, o));
      const float mn = fmaxf(m_run[r], tmax);
      alpha[r] = __expf(m_run[r] - mn);
      m_run[r] = mn;
    }
#pragma unroll
    for (int r = 0; r < 4; ++r) {
      p[0][r] = __expf(p[0][r] - m_run[r]);
      p[1][r] = __expf(p[1][r] - m_run[r]);
      float s = p[0][r] + p[1][r];
#pragma unroll
      for (int o = 1; o <= 8; o <<= 1) s += __shfl_xor(s, o);
      l_run[r] = l_run[r] * alpha[r] + s;
    }
#pragma unroll
    for (int i = 0; i < 8; ++i)
#pragma unroll
      for (int r = 0; r < 4; ++r) o_acc[i][r] *= alpha[r];
    // ---- P -> LDS (bf16, A-fragment layout for PV) ----
    {
      unsigned short* pw = P_lds + wave * 640;
#pragma unroll
      for (int n = 0; n < 2; ++n)
#pragma unroll
        for (int r = 0; r < 4; ++r)
          pw[(((lane >> 4) << 2) + r) * 40 + n * 16 + (lane & 15)] = f2bf(p[n][r]);
    }
    __syncthreads();

    // ---- O += P V ----
    const short8 pa = *(const short8*)((const char*)P_lds + wave * 1280 +
                        (lane & 15) * 80 + ((lane >> 4) << 4));
#pragma unroll
    for (int d8 = 0; d8 < 8; ++d8) {
      const short8 vb = *(const short8*)((const char*)Vt_lds +
                          (d8 * 16 + (lane & 15)) * 80 + ((lane >> 4) << 4));
      o_acc[d8] = MFMA16(pa, vb, o_acc[d8], 0, 0, 0);
    }
    __syncthreads();
  }

  // epilogue: O / l
#pragma unroll
  for (int d8 = 0; d8 < 8; ++d8) {
#pragma unroll
    for (int r = 0; r < 4; ++r) {
      const int row = brow + qrow_w + ((lane >> 4) << 2) + r;
      Oh[(size_t)row * 512 + h * 128 + d8 * 16 + (lane & 15)] =
          f2bf(o_acc[d8][r] / l_run[r]);
    }
  }
}

// ---------------------------------------------------------------------------
extern "C" void kernel_launch(void* const* d_in, const int* in_sizes, int n_in,
                              void* d_out, int out_size, void* d_ws, size_t ws_size,
                              hipStream_t stream) {
  const float* Q  = (const float*)d_in[0];
  const float* K_ = (const float*)d_in[1];
  const float* V  = (const float*)d_in[2];
  const float* Wq = (const float*)d_in[3];
  const float* Wk = (const float*)d_in[4];
  const float* Wv = (const float*)d_in[5];
  const float* Wo = (const float*)d_in[6];
  float* out = (float*)d_out;

  // ws layout (bytes):
  //   0        : Wt   3 x [512][2048] bf16  (Wq group-summed, Wk, Wv; N-major)
  //   6291456  : WoT  [2048][512] bf16
  //   8388608  : qh/kh/vh/Oh 4 x [4096][512] bf16
  // total 25165824 bytes
  char* ws = (char*)d_ws;
  unsigned short* Wt  = (unsigned short*)ws;
  unsigned short* WoT = (unsigned short*)(ws + 6291456);
  unsigned short* qh  = (unsigned short*)(ws + 8388608);
  unsigned short* kh  = qh + 2097152;
  unsigned short* vh  = qh + 2 * 2097152;
  unsigned short* Oh  = qh + 3 * 2097152;

  // weight prep
  wqsum_t<<<dim3(8, 32), 256, 0, stream>>>(Wq, Wt);
  transpose_w<<<dim3(8, 32), 256, 0, stream>>>(Wk, Wt + 1048576, 2048, 512);
  transpose_w<<<dim3(8, 32), 256, 0, stream>>>(Wv, Wt + 2097152, 2048, 512);
  transpose_w<<<dim3(32, 8), 256, 0, stream>>>(Wo, WoT, 512, 2048);

  // q/k/v projections (batched over z: A in {Q,K,V}, B in Wt blocks)
  gemm_bt<true, unsigned short><<<dim3(4, 32, 3), 256, 0, stream>>>(
      Q, K_, V, Wt, qh, /*K=*/2048, /*N=*/512, /*sB=*/1048576, /*sC=*/2097152);

  // causal GQA attention
  attn_fwd<<<dim3(32, 4, 2), 256, 0, stream>>>(qh, kh, vh, Oh);

  // output projection
  gemm_bt<false, float><<<dim3(16, 32, 1), 256, 0, stream>>>(
      Oh, Oh, Oh, WoT, out, /*K=*/512, /*N=*/2048, /*sB=*/0, /*sC=*/0);
}

// Round 2
// 198.141 us; speedup vs baseline: 1.1565x; 1.1565x over previous
//
#include <hip/hip_runtime.h>
#include <hip/hip_bf16.h>

typedef __attribute__((ext_vector_type(8))) short short8;
typedef __attribute__((ext_vector_type(4))) float f32x4;

#define MFMA16 __builtin_amdgcn_mfma_f32_16x16x32_bf16

__device__ inline unsigned short f2bf(float f) {
  __hip_bfloat16 h = __float2bfloat16(f);
  unsigned short u;
  __builtin_memcpy(&u, &h, 2);
  return u;
}

__device__ inline float bf2f(unsigned short u) {
  unsigned int x = ((unsigned int)u) << 16;
  float f;
  __builtin_memcpy(&f, &x, 4);
  return f;
}

__device__ inline void storeC(unsigned short* p, float v) { *p = f2bf(v); }
__device__ inline void storeC(float* p, float v) { *p = v; }

__device__ inline void gload16(const void* g, void* l) {
  __builtin_amdgcn_global_load_lds(
      (const __attribute__((address_space(1))) unsigned int*)g,
      (__attribute__((address_space(3))) unsigned int*)l,
      16, 0, 0);
}

// ---------------------------------------------------------------------------
// Weight prep: dst[n][d] = sum_g Wq[d][n + g*512], bf16 out. 512x2048 output.
__global__ __launch_bounds__(256)
void wqsum_t(const float* __restrict__ wq, unsigned short* __restrict__ dst) {
  __shared__ float t[64][65];
  const int n0 = blockIdx.x * 64, d0 = blockIdx.y * 64;
  const int tid = threadIdx.x;
#pragma unroll
  for (int it = 0; it < 16; ++it) {
    const int idx = it * 256 + tid;
    const int dd = idx >> 6, nn = idx & 63;
    const float* p = wq + (size_t)(d0 + dd) * 2048 + n0 + nn;
    t[dd][nn] = p[0] + p[512] + p[1024] + p[1536];
  }
  __syncthreads();
#pragma unroll
  for (int it = 0; it < 16; ++it) {
    const int idx = it * 256 + tid;
    const int nn = idx >> 6, dd = idx & 63;
    dst[(size_t)(n0 + nn) * 2048 + d0 + dd] = f2bf(t[dd][nn]);
  }
}

// Generic transpose+convert: dst[c][r] = src[r][c], src is R x C f32.
__global__ __launch_bounds__(256)
void transpose_w(const float* __restrict__ src, unsigned short* __restrict__ dst,
                 int R, int C) {
  __shared__ float t[64][65];
  const int c0 = blockIdx.x * 64, r0 = blockIdx.y * 64;
  const int tid = threadIdx.x;
#pragma unroll
  for (int it = 0; it < 16; ++it) {
    const int idx = it * 256 + tid;
    const int r = idx >> 6, c = idx & 63;
    t[r][c] = src[(size_t)(r0 + r) * C + c0 + c];
  }
  __syncthreads();
#pragma unroll
  for (int it = 0; it < 16; ++it) {
    const int idx = it * 256 + tid;
    const int rr = idx >> 6, cc = idx & 63;
    dst[(size_t)(c0 + rr) * R + r0 + cc] = f2bf(t[cc][rr]);
  }
}

// V transpose: vt[bh][d][s] = vh[brow+s][h*128+d]. grid(32, 2, 8).
__global__ __launch_bounds__(256)
void vtrans(const unsigned short* __restrict__ vh, unsigned short* __restrict__ vt) {
  __shared__ unsigned short t[64][72];
  const int s0 = blockIdx.x * 64;
  const int d0 = blockIdx.y * 64;
  const int bh = blockIdx.z;
  const int brow = (bh >> 2) * 2048;
  const int h = bh & 3;
  const int tid = threadIdx.x;
#pragma unroll
  for (int it = 0; it < 2; ++it) {
    const int idx = it * 256 + tid;
    const int s = idx >> 3;
    const int dd = (idx & 7) << 3;
    *(short8*)&t[s][dd] =
        *(const short8*)(vh + (size_t)(brow + s0 + s) * 512 + h * 128 + d0 + dd);
  }
  __syncthreads();
#pragma unroll
  for (int it = 0; it < 2; ++it) {
    const int idx = it * 256 + tid;
    const int dd = idx >> 3;
    const int ss = (idx & 7) << 3;
    short8 o;
#pragma unroll
    for (int e = 0; e < 8; ++e) o[e] = (short)t[ss + e][dd];
    *(short8*)(vt + ((size_t)bh * 128 + d0 + dd) * 2048 + s0 + ss) = o;
  }
}

// ---------------------------------------------------------------------------
// GEMM C[M,N] = A[M,K] * Bt[N,K]^T. 128x128 tile, BK=64, 4 waves.
template <bool AF32, typename CT>
__global__ __launch_bounds__(256)
void gemm_bt(const void* A0, const void* A1, const void* A2,
             const unsigned short* __restrict__ Bt, CT* __restrict__ C,
             int K, int N, size_t sB, size_t sC) {
  __shared__ unsigned short As[128 * 64];
  __shared__ unsigned short Bs[128 * 64];

  const int tid = threadIdx.x;
  const int lane = tid & 63;
  const int wv = tid >> 6;
  const int wm = (wv >> 1) << 6;
  const int wn = (wv & 1) << 6;
  const int z = blockIdx.z;
  const int m0 = blockIdx.y * 128;
  const int n0 = blockIdx.x * 128;

  const void* Az = (z == 0) ? A0 : (z == 1) ? A1 : A2;
  const unsigned short* Ab = (const unsigned short*)Az;
  const float* Af = (const float*)Az;
  const unsigned short* Bz = Bt + sB * (size_t)z;

  const f32x4 zero = {0.f, 0.f, 0.f, 0.f};
  f32x4 acc[4][4];
#pragma unroll
  for (int i = 0; i < 4; ++i)
#pragma unroll
    for (int j = 0; j < 4; ++j) acc[i][j] = zero;

  const int srow = tid >> 3;
  const int scol = (tid & 7) << 3;

  for (int k0 = 0; k0 < K; k0 += 64) {
#pragma unroll
    for (int s = 0; s < 4; ++s) {
      const unsigned short* bsrc = Bz + (size_t)(n0 + srow + s * 32) * K + k0 + scol;
      gload16(bsrc, (char*)Bs + tid * 16 + s * 4096);
    }
    if constexpr (AF32) {
#pragma unroll
      for (int s = 0; s < 4; ++s) {
        const float* asrc = Af + (size_t)(m0 + srow + s * 32) * K + k0 + scol;
        const float4 v0 = *(const float4*)(asrc);
        const float4 v1 = *(const float4*)(asrc + 4);
        short8 o;
        o[0] = (short)f2bf(v0.x); o[1] = (short)f2bf(v0.y);
        o[2] = (short)f2bf(v0.z); o[3] = (short)f2bf(v0.w);
        o[4] = (short)f2bf(v1.x); o[5] = (short)f2bf(v1.y);
        o[6] = (short)f2bf(v1.z); o[7] = (short)f2bf(v1.w);
        *(short8*)((char*)As + tid * 16 + s * 4096) = o;
      }
    } else {
#pragma unroll
      for (int s = 0; s < 4; ++s) {
        const unsigned short* asrc = Ab + (size_t)(m0 + srow + s * 32) * K + k0 + scol;
        gload16(asrc, (char*)As + tid * 16 + s * 4096);
      }
    }
    __syncthreads();
#pragma unroll
    for (int kk = 0; kk < 2; ++kk) {
      const int kb = kk * 64 + ((lane >> 4) << 4);
      short8 a[4], b[4];
#pragma unroll
      for (int i = 0; i < 4; ++i)
        a[i] = *(const short8*)((const char*)As + (wm + i * 16 + (lane & 15)) * 128 + kb);
#pragma unroll
      for (int j = 0; j < 4; ++j)
        b[j] = *(const short8*)((const char*)Bs + (wn + j * 16 + (lane & 15)) * 128 + kb);
#pragma unroll
      for (int i = 0; i < 4; ++i)
#pragma unroll
        for (int j = 0; j < 4; ++j)
          acc[i][j] = MFMA16(a[i], b[j], acc[i][j], 0, 0, 0);
    }
    __syncthreads();
  }

  CT* Cz = C + sC * (size_t)z;
#pragma unroll
  for (int i = 0; i < 4; ++i) {
    const int row0 = m0 + wm + i * 16 + ((lane >> 4) << 2);
#pragma unroll
    for (int j = 0; j < 4; ++j) {
      const int col = n0 + wn + j * 16 + (lane & 15);
#pragma unroll
      for (int r = 0; r < 4; ++r)
        storeC(&Cz[(size_t)(row0 + r) * N + col], acc[i][j][r]);
    }
  }
}

// ---------------------------------------------------------------------------
// Split-KV flash attention. Jobs: per bh, qt in 0..31 (64 q rows), KV chunks
// of 256. nchunk(qt) = qt/4+1; 144 jobs/bh -> grid(144, 8), block = 128
// (2 independent waves x 32 q rows). No barriers; K/V^T read from global
// (L2-resident); P transposed through tiny per-wave LDS.
// g==0 jobs (single chunk) write Oh directly; others write pO (bf16,
// unnormalized) + pml (m,l f32) for attn_combine.
__global__ __launch_bounds__(128)
void attn_split(const unsigned short* __restrict__ qh,
                const unsigned short* __restrict__ kh,
                const unsigned short* __restrict__ vt,
                unsigned short* __restrict__ Oh,
                unsigned short* __restrict__ pO,
                float* __restrict__ pml) {
  __shared__ unsigned short P_lds[2][32][36];
  const int tid = threadIdx.x;
  const int lane = tid & 63;
  const int wave = tid >> 6;
  const int l15 = lane & 15;
  const int l4 = lane >> 4;
  const int bh = blockIdx.y;
  const int brow = (bh >> 2) * 2048;
  const int h = bh & 3;

  // decode job -> (qt, chunk)
  int j = blockIdx.x, g = 0;
  while (j >= 2 * (g + 1) * (g + 2)) ++g;
  const int rem = j - 2 * g * (g + 1);
  const int r_ = rem / (g + 1);
  const int c_ = rem - r_ * (g + 1);
  const int qt = 4 * g + r_;
  const int k_begin = c_ << 8;
  const int k_end = (c_ == g) ? (qt + 1) * 64 : ((c_ + 1) << 8);
  const int qrow_w = qt * 64 + wave * 32;
  const float SCALE = 0.08838834764831845f;  // 1/sqrt(128)

  short8 qf[2][4];
#pragma unroll
  for (int m = 0; m < 2; ++m) {
    const unsigned short* qp =
        qh + (size_t)(brow + qrow_w + m * 16 + l15) * 512 + h * 128 + (l4 << 3);
#pragma unroll
    for (int kk = 0; kk < 4; ++kk) qf[m][kk] = *(const short8*)(qp + kk * 32);
  }

  const f32x4 zero = {0.f, 0.f, 0.f, 0.f};
  f32x4 o_acc[2][8];
#pragma unroll
  for (int m = 0; m < 2; ++m)
#pragma unroll
    for (int i = 0; i < 8; ++i) o_acc[m][i] = zero;
  float m_run[2][4], l_run[2][4];
#pragma unroll
  for (int m = 0; m < 2; ++m)
#pragma unroll
    for (int r = 0; r < 4; ++r) { m_run[m][r] = -1e30f; l_run[m][r] = 0.f; }

  const int nt = (k_end - k_begin) >> 5;
  for (int t = 0; t < nt; ++t) {
    const int kbase = k_begin + t * 32;
    // ---- S = Q K^T ----
    f32x4 sa[2][2];
    sa[0][0] = zero; sa[0][1] = zero; sa[1][0] = zero; sa[1][1] = zero;
#pragma unroll
    for (int n = 0; n < 2; ++n) {
      short8 kf[4];
      const unsigned short* kp =
          kh + (size_t)(brow + kbase + n * 16 + l15) * 512 + h * 128 + (l4 << 3);
#pragma unroll
      for (int kk = 0; kk < 4; ++kk) kf[kk] = *(const short8*)(kp + kk * 32);
#pragma unroll
      for (int kk = 0; kk < 4; ++kk) {
        sa[0][n] = MFMA16(qf[0][kk], kf[kk], sa[0][n], 0, 0, 0);
        sa[1][n] = MFMA16(qf[1][kk], kf[kk], sa[1][n], 0, 0, 0);
      }
    }
    // ---- online softmax (rows: m*16 + l4*4 + r; col k: kbase + n*16 + l15) ----
    const bool need_mask = (kbase + 31 > qrow_w);
    float p[2][2][4];
#pragma unroll
    for (int m = 0; m < 2; ++m)
#pragma unroll
      for (int n = 0; n < 2; ++n)
#pragma unroll
        for (int r = 0; r < 4; ++r) {
          float v = sa[m][n][r] * SCALE;
          if (need_mask) {
            const int kc = kbase + n * 16 + l15;
            const int qr = qrow_w + m * 16 + (l4 << 2) + r;
            if (kc > qr) v = -1e30f;
          }
          p[m][n][r] = v;
        }
    float alpha[2][4];
#pragma unroll
    for (int m = 0; m < 2; ++m)
#pragma unroll
      for (int r = 0; r < 4; ++r) {
        float tmax = fmaxf(p[m][0][r], p[m][1][r]);
#pragma unroll
        for (int o = 1; o <= 8; o <<= 1) tmax = fmaxf(tmax, __shfl_xor(tmax, o));
        const float mn = fmaxf(m_run[m][r], tmax);
        alpha[m][r] = __expf(m_run[m][r] - mn);
        m_run[m][r] = mn;
      }
#pragma unroll
    for (int m = 0; m < 2; ++m)
#pragma unroll
      for (int r = 0; r < 4; ++r) {
        p[m][0][r] = __expf(p[m][0][r] - m_run[m][r]);
        p[m][1][r] = __expf(p[m][1][r] - m_run[m][r]);
        float s = p[m][0][r] + p[m][1][r];
#pragma unroll
        for (int o = 1; o <= 8; o <<= 1) s += __shfl_xor(s, o);
        l_run[m][r] = l_run[m][r] * alpha[m][r] + s;
      }
#pragma unroll
    for (int m = 0; m < 2; ++m)
#pragma unroll
      for (int d8 = 0; d8 < 8; ++d8)
#pragma unroll
        for (int r = 0; r < 4; ++r) o_acc[m][d8][r] *= alpha[m][r];
    // ---- P -> per-wave LDS (transpose to A-fragment layout) ----
#pragma unroll
    for (int m = 0; m < 2; ++m)
#pragma unroll
      for (int n = 0; n < 2; ++n)
#pragma unroll
        for (int r = 0; r < 4; ++r)
          P_lds[wave][m * 16 + (l4 << 2) + r][n * 16 + l15] = f2bf(p[m][n][r]);
    short8 pa[2];
#pragma unroll
    for (int m = 0; m < 2; ++m)
      pa[m] = *(const short8*)((const char*)&P_lds[wave][0][0] +
                               (m * 16 + l15) * 72 + (l4 << 4));
    // ---- O += P V (V^T fragments straight from global) ----
#pragma unroll
    for (int d8 = 0; d8 < 8; ++d8) {
      const short8 vb = *(const short8*)(
          vt + ((size_t)bh * 128 + d8 * 16 + l15) * 2048 + kbase + (l4 << 3));
      o_acc[0][d8] = MFMA16(pa[0], vb, o_acc[0][d8], 0, 0, 0);
      o_acc[1][d8] = MFMA16(pa[1], vb, o_acc[1][d8], 0, 0, 0);
    }
  }

  if (g == 0) {
#pragma unroll
    for (int m = 0; m < 2; ++m)
#pragma unroll
      for (int d8 = 0; d8 < 8; ++d8)
#pragma unroll
        for (int r = 0; r < 4; ++r) {
          const int row = brow + qrow_w + m * 16 + (l4 << 2) + r;
          Oh[(size_t)row * 512 + h * 128 + d8 * 16 + l15] =
              f2bf(o_acc[m][d8][r] / l_run[m][r]);
        }
  } else {
    const int slot = bh * 144 + blockIdx.x;
    unsigned short* po = pO + (size_t)slot * 64 * 128;
#pragma unroll
    for (int m = 0; m < 2; ++m)
#pragma unroll
      for (int d8 = 0; d8 < 8; ++d8)
#pragma unroll
        for (int r = 0; r < 4; ++r) {
          const int row = wave * 32 + m * 16 + (l4 << 2) + r;
          po[row * 128 + d8 * 16 + l15] = f2bf(o_acc[m][d8][r]);
        }
    if (l15 == 0) {
#pragma unroll
      for (int m = 0; m < 2; ++m)
#pragma unroll
        for (int r = 0; r < 4; ++r) {
          const int row = wave * 32 + m * 16 + (l4 << 2) + r;
          pml[((size_t)slot * 64 + row) * 2 + 0] = m_run[m][r];
          pml[((size_t)slot * 64 + row) * 2 + 1] = l_run[m][r];
        }
    }
  }
}

// Combine partials for qt >= 4. grid(28, 8), block 256.
__global__ __launch_bounds__(256)
void attn_combine(const unsigned short* __restrict__ pO,
                  const float* __restrict__ pml,
                  unsigned short* __restrict__ Oh) {
  const int bh = blockIdx.y;
  const int qt = 4 + blockIdx.x;
  const int g = qt >> 2;
  const int nch = g + 1;
  const int base = 2 * g * (g + 1) + (qt & 3) * (g + 1);
  const int slot0 = bh * 144 + base;
  const int brow = (bh >> 2) * 2048;
  const int h = bh & 3;
#pragma unroll
  for (int u = 0; u < 4; ++u) {
    const int unit = u * 256 + threadIdx.x;
    const int row = unit >> 4;
    const int c8 = (unit & 15) << 3;
    float M = -1e30f;
    for (int c = 0; c < nch; ++c)
      M = fmaxf(M, pml[((size_t)(slot0 + c) * 64 + row) * 2]);
    float L = 0.f;
    float acc[8] = {0.f, 0.f, 0.f, 0.f, 0.f, 0.f, 0.f, 0.f};
    for (int c = 0; c < nch; ++c) {
      const float mc = pml[((size_t)(slot0 + c) * 64 + row) * 2];
      const float lc = pml[((size_t)(slot0 + c) * 64 + row) * 2 + 1];
      const float w = __expf(mc - M);
      L += w * lc;
      const short8 ov =
          *(const short8*)(pO + ((size_t)(slot0 + c) * 64 + row) * 128 + c8);
#pragma unroll
      for (int e = 0; e < 8; ++e) acc[e] += w * bf2f((unsigned short)ov[e]);
    }
    const float inv = 1.f / L;
    short8 o;
#pragma unroll
    for (int e = 0; e < 8; ++e) o[e] = (short)f2bf(acc[e] * inv);
    *(short8*)(Oh + (size_t)(brow + qt * 64 + row) * 512 + h * 128 + c8) = o;
  }
}

// ---------------------------------------------------------------------------
extern "C" void kernel_launch(void* const* d_in, const int* in_sizes, int n_in,
                              void* d_out, int out_size, void* d_ws, size_t ws_size,
                              hipStream_t stream) {
  const float* Q  = (const float*)d_in[0];
  const float* K_ = (const float*)d_in[1];
  const float* V  = (const float*)d_in[2];
  const float* Wq = (const float*)d_in[3];
  const float* Wk = (const float*)d_in[4];
  const float* Wv = (const float*)d_in[5];
  const float* Wo = (const float*)d_in[6];
  float* out = (float*)d_out;

  // ws layout (bytes):
  //   0         : Wt   3 x [512][2048] bf16
  //   6291456   : WoT  [2048][512] bf16
  //   8388608   : qh/kh/vh/Oh 4 x [4096][512] bf16
  //   25165824  : vt   [8][128][2048] bf16
  //   29360128  : pO   [1152][64][128] bf16 (unnormalized partial O)
  //   48234496  : pml  [1152][64][2] f32
  //   total ~48.9 MB
  char* ws = (char*)d_ws;
  unsigned short* Wt  = (unsigned short*)ws;
  unsigned short* WoT = (unsigned short*)(ws + 6291456);
  unsigned short* qh  = (unsigned short*)(ws + 8388608);
  unsigned short* kh  = qh + 2097152;
  unsigned short* vh  = qh + 2 * 2097152;
  unsigned short* Oh  = qh + 3 * 2097152;
  unsigned short* vt  = (unsigned short*)(ws + 25165824);
  unsigned short* pO  = (unsigned short*)(ws + 29360128);
  float*          pml = (float*)(ws + 48234496);

  // weight prep
  wqsum_t<<<dim3(8, 32), 256, 0, stream>>>(Wq, Wt);
  transpose_w<<<dim3(8, 32), 256, 0, stream>>>(Wk, Wt + 1048576, 2048, 512);
  transpose_w<<<dim3(8, 32), 256, 0, stream>>>(Wv, Wt + 2097152, 2048, 512);
  transpose_w<<<dim3(32, 8), 256, 0, stream>>>(Wo, WoT, 512, 2048);

  // q/k/v projections
  gemm_bt<true, unsigned short><<<dim3(4, 32, 3), 256, 0, stream>>>(
      Q, K_, V, Wt, qh, /*K=*/2048, /*N=*/512, /*sB=*/1048576, /*sC=*/2097152);

  // V^T for the PV B-operand
  vtrans<<<dim3(32, 2, 8), 256, 0, stream>>>(vh, vt);

  // split-KV causal attention + combine
  attn_split<<<dim3(144, 8), 128, 0, stream>>>(qh, kh, vt, Oh, pO, pml);
  attn_combine<<<dim3(28, 8), 256, 0, stream>>>(pO, pml, Oh);

  // output projection
  gemm_bt<false, float><<<dim3(16, 32, 1), 256, 0, stream>>>(
      Oh, Oh, Oh, WoT, out, /*K=*/512, /*N=*/2048, /*sB=*/0, /*sC=*/0);
}

// Round 3
// 169.731 us; speedup vs baseline: 1.3501x; 1.1674x over previous
//
#include <hip/hip_runtime.h>
#include <hip/hip_bf16.h>

typedef __attribute__((ext_vector_type(8))) short short8;
typedef __attribute__((ext_vector_type(4))) float f32x4;

#define MFMA16 __builtin_amdgcn_mfma_f32_16x16x32_bf16

__device__ inline unsigned short f2bf(float f) {
  __hip_bfloat16 h = __float2bfloat16(f);
  unsigned short u;
  __builtin_memcpy(&u, &h, 2);
  return u;
}

__device__ inline float bf2f(unsigned short u) {
  unsigned int x = ((unsigned int)u) << 16;
  float f;
  __builtin_memcpy(&f, &x, 4);
  return f;
}

__device__ inline void storeC(unsigned short* p, float v) { *p = f2bf(v); }
__device__ inline void storeC(float* p, float v) { *p = v; }

__device__ inline void gload16(const void* g, void* l) {
  __builtin_amdgcn_global_load_lds(
      (const __attribute__((address_space(1))) unsigned int*)g,
      (__attribute__((address_space(3))) unsigned int*)l,
      16, 0, 0);
}

// ---------------------------------------------------------------------------
// Weight prep: dst[n][d] = sum_g Wq[d][n + g*512], bf16 out. 512x2048 output.
__global__ __launch_bounds__(256)
void wqsum_t(const float* __restrict__ wq, unsigned short* __restrict__ dst) {
  __shared__ float t[64][65];
  const int n0 = blockIdx.x * 64, d0 = blockIdx.y * 64;
  const int tid = threadIdx.x;
#pragma unroll
  for (int it = 0; it < 16; ++it) {
    const int idx = it * 256 + tid;
    const int dd = idx >> 6, nn = idx & 63;
    const float* p = wq + (size_t)(d0 + dd) * 2048 + n0 + nn;
    t[dd][nn] = p[0] + p[512] + p[1024] + p[1536];
  }
  __syncthreads();
#pragma unroll
  for (int it = 0; it < 16; ++it) {
    const int idx = it * 256 + tid;
    const int nn = idx >> 6, dd = idx & 63;
    dst[(size_t)(n0 + nn) * 2048 + d0 + dd] = f2bf(t[dd][nn]);
  }
}

// Generic transpose+convert: dst[c][r] = src[r][c], src is R x C f32.
__global__ __launch_bounds__(256)
void transpose_w(const float* __restrict__ src, unsigned short* __restrict__ dst,
                 int R, int C) {
  __shared__ float t[64][65];
  const int c0 = blockIdx.x * 64, r0 = blockIdx.y * 64;
  const int tid = threadIdx.x;
#pragma unroll
  for (int it = 0; it < 16; ++it) {
    const int idx = it * 256 + tid;
    const int r = idx >> 6, c = idx & 63;
    t[r][c] = src[(size_t)(r0 + r) * C + c0 + c];
  }
  __syncthreads();
#pragma unroll
  for (int it = 0; it < 16; ++it) {
    const int idx = it * 256 + tid;
    const int rr = idx >> 6, cc = idx & 63;
    dst[(size_t)(c0 + rr) * R + r0 + cc] = f2bf(t[cc][rr]);
  }
}

// V transpose: vt[bh][d][s] = vh[brow+s][h*128+d]. grid(32, 2, 8).
__global__ __launch_bounds__(256)
void vtrans(const unsigned short* __restrict__ vh, unsigned short* __restrict__ vt) {
  __shared__ unsigned short t[64][72];
  const int s0 = blockIdx.x * 64;
  const int d0 = blockIdx.y * 64;
  const int bh = blockIdx.z;
  const int brow = (bh >> 2) * 2048;
  const int h = bh & 3;
  const int tid = threadIdx.x;
#pragma unroll
  for (int it = 0; it < 2; ++it) {
    const int idx = it * 256 + tid;
    const int s = idx >> 3;
    const int dd = (idx & 7) << 3;
    *(short8*)&t[s][dd] =
        *(const short8*)(vh + (size_t)(brow + s0 + s) * 512 + h * 128 + d0 + dd);
  }
  __syncthreads();
#pragma unroll
  for (int it = 0; it < 2; ++it) {
    const int idx = it * 256 + tid;
    const int dd = idx >> 3;
    const int ss = (idx & 7) << 3;
    short8 o;
#pragma unroll
    for (int e = 0; e < 8; ++e) o[e] = (short)t[ss + e][dd];
    *(short8*)(vt + ((size_t)bh * 128 + d0 + dd) * 2048 + s0 + ss) = o;
  }
}

// ---------------------------------------------------------------------------
// GEMM C[M,N] = A[M,K] * Bt[N,K]^T. M=4096 (32 m-tiles of 128), BK=64,
// BN template (64 or 128). Double-buffered LDS, prefetch-before-compute,
// bijective XCD swizzle with n-tiles innermost (A-panel L2 locality).
// 1D grid = nz * 32 * (N/BN); 4 waves (2m x 2n).
template <bool AF32, typename CT, int BN>
__global__ __launch_bounds__(256)
void gemm_bt(const void* A0, const void* A1, const void* A2,
             const unsigned short* __restrict__ Bt, CT* __restrict__ C,
             int K, int N, size_t sB, size_t sC) {
  constexpr int NJ = BN / 32;  // acc cols per wave; B gload16s per thread
  __shared__ unsigned short As[2][128 * 64];
  __shared__ unsigned short Bs[2][BN * 64];

  const int tid = threadIdx.x;
  const int lane = tid & 63;
  const int wv = tid >> 6;
  const int wm = (wv >> 1) << 6;
  const int wn = (wv & 1) * (BN / 2);

  // XCD-aware swizzle (nwg % 8 == 0 in all uses)
  const int nwg = gridDim.x;
  const int bid = blockIdx.x;
  const int job = (bid & 7) * (nwg >> 3) + (bid >> 3);
  const int ntile = N / BN;
  const int z = job / (32 * ntile);
  const int rem = job - z * 32 * ntile;
  const int m0 = (rem / ntile) << 7;
  const int n0 = (rem % ntile) * BN;

  const void* Az = (z == 0) ? A0 : (z == 1) ? A1 : A2;
  const unsigned short* Ab = (const unsigned short*)Az;
  const float* Af = (const float*)Az;
  const unsigned short* Bz = Bt + sB * (size_t)z;

  const f32x4 zero = {0.f, 0.f, 0.f, 0.f};
  f32x4 acc[4][NJ];
#pragma unroll
  for (int i = 0; i < 4; ++i)
#pragma unroll
    for (int j = 0; j < NJ; ++j) acc[i][j] = zero;

  const int srow = tid >> 3;        // 0..31 (+32 per issue)
  const int scol = (tid & 7) << 3;  // element col, 0..56 step 8

  float4 ar[8];  // A f32 prefetch registers (AF32 path)

  auto issueB = [&](int buf, int k0) {
#pragma unroll
    for (int s = 0; s < NJ; ++s) {
      const unsigned short* bsrc = Bz + (size_t)(n0 + srow + s * 32) * K + k0 + scol;
      gload16(bsrc, (char*)&Bs[buf][0] + tid * 16 + s * 4096);
    }
  };
  auto issueA16 = [&](int buf, int k0) {
#pragma unroll
    for (int s = 0; s < 4; ++s) {
      const unsigned short* asrc = Ab + (size_t)(m0 + srow + s * 32) * K + k0 + scol;
      gload16(asrc, (char*)&As[buf][0] + tid * 16 + s * 4096);
    }
  };
  auto loadA = [&](int k0) {
#pragma unroll
    for (int s = 0; s < 4; ++s) {
      const float* asrc = Af + (size_t)(m0 + srow + s * 32) * K + k0 + scol;
      ar[2 * s] = *(const float4*)(asrc);
      ar[2 * s + 1] = *(const float4*)(asrc + 4);
    }
  };
  auto writeA = [&](int buf) {
#pragma unroll
    for (int s = 0; s < 4; ++s) {
      short8 o;
      o[0] = (short)f2bf(ar[2 * s].x); o[1] = (short)f2bf(ar[2 * s].y);
      o[2] = (short)f2bf(ar[2 * s].z); o[3] = (short)f2bf(ar[2 * s].w);
      o[4] = (short)f2bf(ar[2 * s + 1].x); o[5] = (short)f2bf(ar[2 * s + 1].y);
      o[6] = (short)f2bf(ar[2 * s + 1].z); o[7] = (short)f2bf(ar[2 * s + 1].w);
      *(short8*)((char*)&As[buf][0] + tid * 16 + s * 4096) = o;
    }
  };

  // prologue: stage tile 0
  if constexpr (AF32) loadA(0); else issueA16(0, 0);
  issueB(0, 0);
  if constexpr (AF32) writeA(0);
  __syncthreads();

  int cur = 0;
  for (int k0 = 0; k0 < K; k0 += 64) {
    const int nxt = cur ^ 1;
    const bool more = (k0 + 64 < K);
    if (more) {  // issue next tile BEFORE compute (latency hides under MFMA)
      if constexpr (AF32) loadA(k0 + 64); else issueA16(nxt, k0 + 64);
      issueB(nxt, k0 + 64);
    }
#pragma unroll
    for (int kk = 0; kk < 2; ++kk) {
      const int kb = kk * 64 + ((lane >> 4) << 4);
      short8 a[4], b[NJ];
#pragma unroll
      for (int i = 0; i < 4; ++i)
        a[i] = *(const short8*)((const char*)&As[cur][0] +
                                (wm + i * 16 + (lane & 15)) * 128 + kb);
#pragma unroll
      for (int j = 0; j < NJ; ++j)
        b[j] = *(const short8*)((const char*)&Bs[cur][0] +
                                (wn + j * 16 + (lane & 15)) * 128 + kb);
#pragma unroll
      for (int i = 0; i < 4; ++i)
#pragma unroll
        for (int j = 0; j < NJ; ++j)
          acc[i][j] = MFMA16(a[i], b[j], acc[i][j], 0, 0, 0);
    }
    if (more) {
      if constexpr (AF32) writeA(nxt);  // convert+write after compute
    }
    __syncthreads();
    cur = nxt;
  }

  CT* Cz = C + sC * (size_t)z;
#pragma unroll
  for (int i = 0; i < 4; ++i) {
    const int row0 = m0 + wm + i * 16 + ((lane >> 4) << 2);
#pragma unroll
    for (int j = 0; j < NJ; ++j) {
      const int col = n0 + wn + j * 16 + (lane & 15);
#pragma unroll
      for (int r = 0; r < 4; ++r)
        storeC(&Cz[(size_t)(row0 + r) * N + col], acc[i][j][r]);
    }
  }
}

// ---------------------------------------------------------------------------
// Split-KV flash attention. Jobs: per bh, qt in 0..31 (64 q rows), KV chunks
// of 256. grid(144, 8), block = 128 (2 independent waves x 32 q rows).
__global__ __launch_bounds__(128)
void attn_split(const unsigned short* __restrict__ qh,
                const unsigned short* __restrict__ kh,
                const unsigned short* __restrict__ vt,
                unsigned short* __restrict__ Oh,
                unsigned short* __restrict__ pO,
                float* __restrict__ pml) {
  __shared__ unsigned short P_lds[2][32][36];
  const int tid = threadIdx.x;
  const int lane = tid & 63;
  const int wave = tid >> 6;
  const int l15 = lane & 15;
  const int l4 = lane >> 4;
  const int bh = blockIdx.y;
  const int brow = (bh >> 2) * 2048;
  const int h = bh & 3;

  int j = blockIdx.x, g = 0;
  while (j >= 2 * (g + 1) * (g + 2)) ++g;
  const int rem = j - 2 * g * (g + 1);
  const int r_ = rem / (g + 1);
  const int c_ = rem - r_ * (g + 1);
  const int qt = 4 * g + r_;
  const int k_begin = c_ << 8;
  const int k_end = (c_ == g) ? (qt + 1) * 64 : ((c_ + 1) << 8);
  const int qrow_w = qt * 64 + wave * 32;
  const float SCALE = 0.08838834764831845f;  // 1/sqrt(128)

  short8 qf[2][4];
#pragma unroll
  for (int m = 0; m < 2; ++m) {
    const unsigned short* qp =
        qh + (size_t)(brow + qrow_w + m * 16 + l15) * 512 + h * 128 + (l4 << 3);
#pragma unroll
    for (int kk = 0; kk < 4; ++kk) qf[m][kk] = *(const short8*)(qp + kk * 32);
  }

  const f32x4 zero = {0.f, 0.f, 0.f, 0.f};
  f32x4 o_acc[2][8];
#pragma unroll
  for (int m = 0; m < 2; ++m)
#pragma unroll
    for (int i = 0; i < 8; ++i) o_acc[m][i] = zero;
  float m_run[2][4], l_run[2][4];
#pragma unroll
  for (int m = 0; m < 2; ++m)
#pragma unroll
    for (int r = 0; r < 4; ++r) { m_run[m][r] = -1e30f; l_run[m][r] = 0.f; }

  const int nt = (k_end - k_begin) >> 5;
  for (int t = 0; t < nt; ++t) {
    const int kbase = k_begin + t * 32;
    f32x4 sa[2][2];
    sa[0][0] = zero; sa[0][1] = zero; sa[1][0] = zero; sa[1][1] = zero;
#pragma unroll
    for (int n = 0; n < 2; ++n) {
      short8 kf[4];
      const unsigned short* kp =
          kh + (size_t)(brow + kbase + n * 16 + l15) * 512 + h * 128 + (l4 << 3);
#pragma unroll
      for (int kk = 0; kk < 4; ++kk) kf[kk] = *(const short8*)(kp + kk * 32);
#pragma unroll
      for (int kk = 0; kk < 4; ++kk) {
        sa[0][n] = MFMA16(qf[0][kk], kf[kk], sa[0][n], 0, 0, 0);
        sa[1][n] = MFMA16(qf[1][kk], kf[kk], sa[1][n], 0, 0, 0);
      }
    }
    const bool need_mask = (kbase + 31 > qrow_w);
    float p[2][2][4];
#pragma unroll
    for (int m = 0; m < 2; ++m)
#pragma unroll
      for (int n = 0; n < 2; ++n)
#pragma unroll
        for (int r = 0; r < 4; ++r) {
          float v = sa[m][n][r] * SCALE;
          if (need_mask) {
            const int kc = kbase + n * 16 + l15;
            const int qr = qrow_w + m * 16 + (l4 << 2) + r;
            if (kc > qr) v = -1e30f;
          }
          p[m][n][r] = v;
        }
    float alpha[2][4];
#pragma unroll
    for (int m = 0; m < 2; ++m)
#pragma unroll
      for (int r = 0; r < 4; ++r) {
        float tmax = fmaxf(p[m][0][r], p[m][1][r]);
#pragma unroll
        for (int o = 1; o <= 8; o <<= 1) tmax = fmaxf(tmax, __shfl_xor(tmax, o));
        const float mn = fmaxf(m_run[m][r], tmax);
        alpha[m][r] = __expf(m_run[m][r] - mn);
        m_run[m][r] = mn;
      }
#pragma unroll
    for (int m = 0; m < 2; ++m)
#pragma unroll
      for (int r = 0; r < 4; ++r) {
        p[m][0][r] = __expf(p[m][0][r] - m_run[m][r]);
        p[m][1][r] = __expf(p[m][1][r] - m_run[m][r]);
        float s = p[m][0][r] + p[m][1][r];
#pragma unroll
        for (int o = 1; o <= 8; o <<= 1) s += __shfl_xor(s, o);
        l_run[m][r] = l_run[m][r] * alpha[m][r] + s;
      }
#pragma unroll
    for (int m = 0; m < 2; ++m)
#pragma unroll
      for (int d8 = 0; d8 < 8; ++d8)
#pragma unroll
        for (int r = 0; r < 4; ++r) o_acc[m][d8][r] *= alpha[m][r];
#pragma unroll
    for (int m = 0; m < 2; ++m)
#pragma unroll
      for (int n = 0; n < 2; ++n)
#pragma unroll
        for (int r = 0; r < 4; ++r)
          P_lds[wave][m * 16 + (l4 << 2) + r][n * 16 + l15] = f2bf(p[m][n][r]);
    short8 pa[2];
#pragma unroll
    for (int m = 0; m < 2; ++m)
      pa[m] = *(const short8*)((const char*)&P_lds[wave][0][0] +
                               (m * 16 + l15) * 72 + (l4 << 4));
#pragma unroll
    for (int d8 = 0; d8 < 8; ++d8) {
      const short8 vb = *(const short8*)(
          vt + ((size_t)bh * 128 + d8 * 16 + l15) * 2048 + kbase + (l4 << 3));
      o_acc[0][d8] = MFMA16(pa[0], vb, o_acc[0][d8], 0, 0, 0);
      o_acc[1][d8] = MFMA16(pa[1], vb, o_acc[1][d8], 0, 0, 0);
    }
  }

  if (g == 0) {
#pragma unroll
    for (int m = 0; m < 2; ++m)
#pragma unroll
      for (int d8 = 0; d8 < 8; ++d8)
#pragma unroll
        for (int r = 0; r < 4; ++r) {
          const int row = brow + qrow_w + m * 16 + (l4 << 2) + r;
          Oh[(size_t)row * 512 + h * 128 + d8 * 16 + l15] =
              f2bf(o_acc[m][d8][r] / l_run[m][r]);
        }
  } else {
    const int slot = bh * 144 + blockIdx.x;
    unsigned short* po = pO + (size_t)slot * 64 * 128;
#pragma unroll
    for (int m = 0; m < 2; ++m)
#pragma unroll
      for (int d8 = 0; d8 < 8; ++d8)
#pragma unroll
        for (int r = 0; r < 4; ++r) {
          const int row = wave * 32 + m * 16 + (l4 << 2) + r;
          po[row * 128 + d8 * 16 + l15] = f2bf(o_acc[m][d8][r]);
        }
    if (l15 == 0) {
#pragma unroll
      for (int m = 0; m < 2; ++m)
#pragma unroll
        for (int r = 0; r < 4; ++r) {
          const int row = wave * 32 + m * 16 + (l4 << 2) + r;
          pml[((size_t)slot * 64 + row) * 2 + 0] = m_run[m][r];
          pml[((size_t)slot * 64 + row) * 2 + 1] = l_run[m][r];
        }
    }
  }
}

// Combine partials for qt >= 4. grid(28, 8), block 256.
__global__ __launch_bounds__(256)
void attn_combine(const unsigned short* __restrict__ pO,
                  const float* __restrict__ pml,
                  unsigned short* __restrict__ Oh) {
  const int bh = blockIdx.y;
  const int qt = 4 + blockIdx.x;
  const int g = qt >> 2;
  const int nch = g + 1;
  const int base = 2 * g * (g + 1) + (qt & 3) * (g + 1);
  const int slot0 = bh * 144 + base;
  const int brow = (bh >> 2) * 2048;
  const int h = bh & 3;
#pragma unroll
  for (int u = 0; u < 4; ++u) {
    const int unit = u * 256 + threadIdx.x;
    const int row = unit >> 4;
    const int c8 = (unit & 15) << 3;
    float M = -1e30f;
    for (int c = 0; c < nch; ++c)
      M = fmaxf(M, pml[((size_t)(slot0 + c) * 64 + row) * 2]);
    float L = 0.f;
    float acc[8] = {0.f, 0.f, 0.f, 0.f, 0.f, 0.f, 0.f, 0.f};
    for (int c = 0; c < nch; ++c) {
      const float mc = pml[((size_t)(slot0 + c) * 64 + row) * 2];
      const float lc = pml[((size_t)(slot0 + c) * 64 + row) * 2 + 1];
      const float w = __expf(mc - M);
      L += w * lc;
      const short8 ov =
          *(const short8*)(pO + ((size_t)(slot0 + c) * 64 + row) * 128 + c8);
#pragma unroll
      for (int e = 0; e < 8; ++e) acc[e] += w * bf2f((unsigned short)ov[e]);
    }
    const float inv = 1.f / L;
    short8 o;
#pragma unroll
    for (int e = 0; e < 8; ++e) o[e] = (short)f2bf(acc[e] * inv);
    *(short8*)(Oh + (size_t)(brow + qt * 64 + row) * 512 + h * 128 + c8) = o;
  }
}

// ---------------------------------------------------------------------------
extern "C" void kernel_launch(void* const* d_in, const int* in_sizes, int n_in,
                              void* d_out, int out_size, void* d_ws, size_t ws_size,
                              hipStream_t stream) {
  const float* Q  = (const float*)d_in[0];
  const float* K_ = (const float*)d_in[1];
  const float* V  = (const float*)d_in[2];
  const float* Wq = (const float*)d_in[3];
  const float* Wk = (const float*)d_in[4];
  const float* Wv = (const float*)d_in[5];
  const float* Wo = (const float*)d_in[6];
  float* out = (float*)d_out;

  // ws layout (bytes):
  //   0         : Wt   3 x [512][2048] bf16
  //   6291456   : WoT  [2048][512] bf16
  //   8388608   : qh/kh/vh/Oh 4 x [4096][512] bf16
  //   25165824  : vt   [8][128][2048] bf16
  //   29360128  : pO   [1152][64][128] bf16
  //   48234496  : pml  [1152][64][2] f32
  char* ws = (char*)d_ws;
  unsigned short* Wt  = (unsigned short*)ws;
  unsigned short* WoT = (unsigned short*)(ws + 6291456);
  unsigned short* qh  = (unsigned short*)(ws + 8388608);
  unsigned short* kh  = qh + 2097152;
  unsigned short* vh  = qh + 2 * 2097152;
  unsigned short* Oh  = qh + 3 * 2097152;
  unsigned short* vt  = (unsigned short*)(ws + 25165824);
  unsigned short* pO  = (unsigned short*)(ws + 29360128);
  float*          pml = (float*)(ws + 48234496);

  // weight prep
  wqsum_t<<<dim3(8, 32), 256, 0, stream>>>(Wq, Wt);
  transpose_w<<<dim3(8, 32), 256, 0, stream>>>(Wk, Wt + 1048576, 2048, 512);
  transpose_w<<<dim3(8, 32), 256, 0, stream>>>(Wv, Wt + 2097152, 2048, 512);
  transpose_w<<<dim3(32, 8), 256, 0, stream>>>(Wo, WoT, 512, 2048);

  // q/k/v projections: BN=64 -> 3*32*8 = 768 blocks (3/CU)
  gemm_bt<true, unsigned short, 64><<<768, 256, 0, stream>>>(
      Q, K_, V, Wt, qh, /*K=*/2048, /*N=*/512, /*sB=*/1048576, /*sC=*/2097152);

  // V^T for the PV B-operand
  vtrans<<<dim3(32, 2, 8), 256, 0, stream>>>(vh, vt);

  // split-KV causal attention + combine
  attn_split<<<dim3(144, 8), 128, 0, stream>>>(qh, kh, vt, Oh, pO, pml);
  attn_combine<<<dim3(28, 8), 256, 0, stream>>>(pO, pml, Oh);

  // output projection: BN=128 -> 1*32*16 = 512 blocks (2/CU)
  gemm_bt<false, float, 128><<<512, 256, 0, stream>>>(
      Oh, Oh, Oh, WoT, out, /*K=*/512, /*N=*/2048, /*sB=*/0, /*sC=*/0);
}

// Round 4
// 168.737 us; speedup vs baseline: 1.3580x; 1.0059x over previous
//
#include <hip/hip_runtime.h>
#include <hip/hip_bf16.h>

typedef __attribute__((ext_vector_type(8))) short short8;
typedef __attribute__((ext_vector_type(4))) float f32x4;

#define MFMA16 __builtin_amdgcn_mfma_f32_16x16x32_bf16

__device__ inline unsigned short f2bf(float f) {
  __hip_bfloat16 h = __float2bfloat16(f);
  unsigned short u;
  __builtin_memcpy(&u, &h, 2);
  return u;
}

__device__ inline float bf2f(unsigned short u) {
  unsigned int x = ((unsigned int)u) << 16;
  float f;
  __builtin_memcpy(&f, &x, 4);
  return f;
}

__device__ inline void storeC(unsigned short* p, float v) { *p = f2bf(v); }
__device__ inline void storeC(float* p, float v) { *p = v; }

__device__ inline void gload16(const void* g, void* l) {
  __builtin_amdgcn_global_load_lds(
      (const __attribute__((address_space(1))) unsigned int*)g,
      (__attribute__((address_space(3))) unsigned int*)l,
      16, 0, 0);
}

// ---------------------------------------------------------------------------
// Weight prep: dst[n][d] = sum_g Wq[d][n + g*512], bf16 out. 512x2048 output.
__global__ __launch_bounds__(256)
void wqsum_t(const float* __restrict__ wq, unsigned short* __restrict__ dst) {
  __shared__ float t[64][65];
  const int n0 = blockIdx.x * 64, d0 = blockIdx.y * 64;
  const int tid = threadIdx.x;
#pragma unroll
  for (int it = 0; it < 16; ++it) {
    const int idx = it * 256 + tid;
    const int dd = idx >> 6, nn = idx & 63;
    const float* p = wq + (size_t)(d0 + dd) * 2048 + n0 + nn;
    t[dd][nn] = p[0] + p[512] + p[1024] + p[1536];
  }
  __syncthreads();
#pragma unroll
  for (int it = 0; it < 16; ++it) {
    const int idx = it * 256 + tid;
    const int nn = idx >> 6, dd = idx & 63;
    dst[(size_t)(n0 + nn) * 2048 + d0 + dd] = f2bf(t[dd][nn]);
  }
}

// Generic transpose+convert: dst[c][r] = src[r][c], src is R x C f32.
__global__ __launch_bounds__(256)
void transpose_w(const float* __restrict__ src, unsigned short* __restrict__ dst,
                 int R, int C) {
  __shared__ float t[64][65];
  const int c0 = blockIdx.x * 64, r0 = blockIdx.y * 64;
  const int tid = threadIdx.x;
#pragma unroll
  for (int it = 0; it < 16; ++it) {
    const int idx = it * 256 + tid;
    const int r = idx >> 6, c = idx & 63;
    t[r][c] = src[(size_t)(r0 + r) * C + c0 + c];
  }
  __syncthreads();
#pragma unroll
  for (int it = 0; it < 16; ++it) {
    const int idx = it * 256 + tid;
    const int rr = idx >> 6, cc = idx & 63;
    dst[(size_t)(c0 + rr) * R + r0 + cc] = f2bf(t[cc][rr]);
  }
}

// V transpose: vt[bh][d][s] = vh[brow+s][h*128+d]. grid(32, 2, 8).
__global__ __launch_bounds__(256)
void vtrans(const unsigned short* __restrict__ vh, unsigned short* __restrict__ vt) {
  __shared__ unsigned short t[64][72];
  const int s0 = blockIdx.x * 64;
  const int d0 = blockIdx.y * 64;
  const int bh = blockIdx.z;
  const int brow = (bh >> 2) * 2048;
  const int h = bh & 3;
  const int tid = threadIdx.x;
#pragma unroll
  for (int it = 0; it < 2; ++it) {
    const int idx = it * 256 + tid;
    const int s = idx >> 3;
    const int dd = (idx & 7) << 3;
    *(short8*)&t[s][dd] =
        *(const short8*)(vh + (size_t)(brow + s0 + s) * 512 + h * 128 + d0 + dd);
  }
  __syncthreads();
#pragma unroll
  for (int it = 0; it < 2; ++it) {
    const int idx = it * 256 + tid;
    const int dd = idx >> 3;
    const int ss = (idx & 7) << 3;
    short8 o;
#pragma unroll
    for (int e = 0; e < 8; ++e) o[e] = (short)t[ss + e][dd];
    *(short8*)(vt + ((size_t)bh * 128 + d0 + dd) * 2048 + s0 + ss) = o;
  }
}

// ---------------------------------------------------------------------------
// GEMM C[M,N] = A[M,K] * Bt[N,K]^T.  m97-structure: 128x128 tile, BK=64,
// 4 waves (2m x 2n, 64x64 each, acc 4x4 = 0.5 ds_read/MFMA), SINGLE-buffered
// 32KB LDS, stage -> bar -> compute -> bar.  T2 XOR swizzle (row&7)<<4 on
// both operands: gload_lds paths pre-swizzle the GLOBAL source col; the f32-A
// reg-staged path swizzles the ds_write dest.  XCD-aware job swizzle.
// 1D grid = nz * 32 * (N/128); grid % 8 == 0.
template <bool AF32, typename CT>
__global__ __launch_bounds__(256)
void gemm_bt(const void* A0, const void* A1, const void* A2,
             const unsigned short* __restrict__ Bt, CT* __restrict__ C,
             int K, int N, size_t sB, size_t sC) {
  __shared__ unsigned short As[128 * 64];
  __shared__ unsigned short Bs[128 * 64];

  const int tid = threadIdx.x;
  const int lane = tid & 63;
  const int wv = tid >> 6;
  const int wm = (wv >> 1) << 6;
  const int wn = (wv & 1) << 6;
  const int l15 = lane & 15;
  const int l4 = lane >> 4;
  const int lsw = (l15 & 7) << 4;  // read-side swizzle (bytes)

  // XCD-aware bijective swizzle (nwg % 8 == 0), n-tiles innermost.
  const int nwg = gridDim.x;
  const int bid = blockIdx.x;
  const int job = (bid & 7) * (nwg >> 3) + (bid >> 3);
  const int ntile = N >> 7;
  const int z = job / (32 * ntile);
  const int rem = job - z * 32 * ntile;
  const int m0 = (rem / ntile) << 7;
  const int n0 = (rem % ntile) << 7;

  const void* Az = (z == 0) ? A0 : (z == 1) ? A1 : A2;
  const unsigned short* Ab = (const unsigned short*)Az;
  const float* Af = (const float*)Az;
  const unsigned short* Bz = Bt + sB * (size_t)z;

  const f32x4 zero = {0.f, 0.f, 0.f, 0.f};
  f32x4 acc[4][4];
#pragma unroll
  for (int i = 0; i < 4; ++i)
#pragma unroll
    for (int j = 0; j < 4; ++j) acc[i][j] = zero;

  const int srow = tid >> 3;                 // 0..31 (+32 per issue)
  const int scol = (tid & 7) << 3;           // element col, 0..56 step 8
  const int scolsw = scol ^ ((srow & 7) << 3);  // swizzled source col (elems)

  float4 ar[8];  // f32-A prefetch regs (AF32 path)

  auto issueB = [&](int k0) {
#pragma unroll
    for (int s = 0; s < 4; ++s) {
      const unsigned short* bsrc =
          Bz + (size_t)(n0 + srow + s * 32) * K + k0 + scolsw;
      gload16(bsrc, (char*)Bs + tid * 16 + s * 4096);
    }
  };
  auto issueA16 = [&](int k0) {
#pragma unroll
    for (int s = 0; s < 4; ++s) {
      const unsigned short* asrc =
          Ab + (size_t)(m0 + srow + s * 32) * K + k0 + scolsw;
      gload16(asrc, (char*)As + tid * 16 + s * 4096);
    }
  };
  auto loadA = [&](int k0) {
#pragma unroll
    for (int s = 0; s < 4; ++s) {
      const float* asrc = Af + (size_t)(m0 + srow + s * 32) * K + k0 + scol;
      ar[2 * s] = *(const float4*)(asrc);
      ar[2 * s + 1] = *(const float4*)(asrc + 4);
    }
  };
  auto writeA = [&]() {
#pragma unroll
    for (int s = 0; s < 4; ++s) {
      short8 o;
      o[0] = (short)f2bf(ar[2 * s].x); o[1] = (short)f2bf(ar[2 * s].y);
      o[2] = (short)f2bf(ar[2 * s].z); o[3] = (short)f2bf(ar[2 * s].w);
      o[4] = (short)f2bf(ar[2 * s + 1].x); o[5] = (short)f2bf(ar[2 * s + 1].y);
      o[6] = (short)f2bf(ar[2 * s + 1].z); o[7] = (short)f2bf(ar[2 * s + 1].w);
      // swizzled dest: row = srow + s*32, byte col = (scol*2) ^ ((srow&7)<<4)
      *(short8*)((char*)As + (srow + s * 32) * 128 + scolsw * 2) = o;
    }
  };

  if constexpr (AF32) loadA(0);

  for (int k0 = 0; k0 < K; k0 += 64) {
    // ---- stage tile k0 (LDS free: previous compute drained at bar2) ----
    if constexpr (AF32) writeA(); else issueA16(k0);
    issueB(k0);
    if constexpr (AF32) {
      if (k0 + 64 < K) loadA(k0 + 64);  // next A f32 -> regs, hides under bar+MFMA
    }
    __syncthreads();
    // ---- compute ----
#pragma unroll
    for (int kk = 0; kk < 2; ++kk) {
      const int kb = (kk * 64 + (l4 << 4)) ^ lsw;
      short8 a[4], b[4];
#pragma unroll
      for (int i = 0; i < 4; ++i)
        a[i] = *(const short8*)((const char*)As + (wm + i * 16 + l15) * 128 + kb);
#pragma unroll
      for (int j = 0; j < 4; ++j)
        b[j] = *(const short8*)((const char*)Bs + (wn + j * 16 + l15) * 128 + kb);
#pragma unroll
      for (int i = 0; i < 4; ++i)
#pragma unroll
        for (int j = 0; j < 4; ++j)
          acc[i][j] = MFMA16(a[i], b[j], acc[i][j], 0, 0, 0);
    }
    __syncthreads();
  }

  CT* Cz = C + sC * (size_t)z;
#pragma unroll
  for (int i = 0; i < 4; ++i) {
    const int row0 = m0 + wm + i * 16 + (l4 << 2);
#pragma unroll
    for (int j = 0; j < 4; ++j) {
      const int col = n0 + wn + j * 16 + l15;
#pragma unroll
      for (int r = 0; r < 4; ++r)
        storeC(&Cz[(size_t)(row0 + r) * N + col], acc[i][j][r]);
    }
  }
}

// ---------------------------------------------------------------------------
// Split-KV flash attention. Jobs: per bh, qt in 0..31 (64 q rows), KV chunks
// of 256. grid(144, 8), block = 128 (2 independent waves x 32 q rows).
__global__ __launch_bounds__(128)
void attn_split(const unsigned short* __restrict__ qh,
                const unsigned short* __restrict__ kh,
                const unsigned short* __restrict__ vt,
                unsigned short* __restrict__ Oh,
                unsigned short* __restrict__ pO,
                float* __restrict__ pml) {
  __shared__ unsigned short P_lds[2][32][36];
  const int tid = threadIdx.x;
  const int lane = tid & 63;
  const int wave = tid >> 6;
  const int l15 = lane & 15;
  const int l4 = lane >> 4;
  const int bh = blockIdx.y;
  const int brow = (bh >> 2) * 2048;
  const int h = bh & 3;

  int j = blockIdx.x, g = 0;
  while (j >= 2 * (g + 1) * (g + 2)) ++g;
  const int rem = j - 2 * g * (g + 1);
  const int r_ = rem / (g + 1);
  const int c_ = rem - r_ * (g + 1);
  const int qt = 4 * g + r_;
  const int k_begin = c_ << 8;
  const int k_end = (c_ == g) ? (qt + 1) * 64 : ((c_ + 1) << 8);
  const int qrow_w = qt * 64 + wave * 32;
  const float SCALE = 0.08838834764831845f;  // 1/sqrt(128)

  short8 qf[2][4];
#pragma unroll
  for (int m = 0; m < 2; ++m) {
    const unsigned short* qp =
        qh + (size_t)(brow + qrow_w + m * 16 + l15) * 512 + h * 128 + (l4 << 3);
#pragma unroll
    for (int kk = 0; kk < 4; ++kk) qf[m][kk] = *(const short8*)(qp + kk * 32);
  }

  const f32x4 zero = {0.f, 0.f, 0.f, 0.f};
  f32x4 o_acc[2][8];
#pragma unroll
  for (int m = 0; m < 2; ++m)
#pragma unroll
    for (int i = 0; i < 8; ++i) o_acc[m][i] = zero;
  float m_run[2][4], l_run[2][4];
#pragma unroll
  for (int m = 0; m < 2; ++m)
#pragma unroll
    for (int r = 0; r < 4; ++r) { m_run[m][r] = -1e30f; l_run[m][r] = 0.f; }

  const int nt = (k_end - k_begin) >> 5;
  for (int t = 0; t < nt; ++t) {
    const int kbase = k_begin + t * 32;
    f32x4 sa[2][2];
    sa[0][0] = zero; sa[0][1] = zero; sa[1][0] = zero; sa[1][1] = zero;
#pragma unroll
    for (int n = 0; n < 2; ++n) {
      short8 kf[4];
      const unsigned short* kp =
          kh + (size_t)(brow + kbase + n * 16 + l15) * 512 + h * 128 + (l4 << 3);
#pragma unroll
      for (int kk = 0; kk < 4; ++kk) kf[kk] = *(const short8*)(kp + kk * 32);
#pragma unroll
      for (int kk = 0; kk < 4; ++kk) {
        sa[0][n] = MFMA16(qf[0][kk], kf[kk], sa[0][n], 0, 0, 0);
        sa[1][n] = MFMA16(qf[1][kk], kf[kk], sa[1][n], 0, 0, 0);
      }
    }
    const bool need_mask = (kbase + 31 > qrow_w);
    float p[2][2][4];
#pragma unroll
    for (int m = 0; m < 2; ++m)
#pragma unroll
      for (int n = 0; n < 2; ++n)
#pragma unroll
        for (int r = 0; r < 4; ++r) {
          float v = sa[m][n][r] * SCALE;
          if (need_mask) {
            const int kc = kbase + n * 16 + l15;
            const int qr = qrow_w + m * 16 + (l4 << 2) + r;
            if (kc > qr) v = -1e30f;
          }
          p[m][n][r] = v;
        }
    float alpha[2][4];
#pragma unroll
    for (int m = 0; m < 2; ++m)
#pragma unroll
      for (int r = 0; r < 4; ++r) {
        float tmax = fmaxf(p[m][0][r], p[m][1][r]);
#pragma unroll
        for (int o = 1; o <= 8; o <<= 1) tmax = fmaxf(tmax, __shfl_xor(tmax, o));
        const float mn = fmaxf(m_run[m][r], tmax);
        alpha[m][r] = __expf(m_run[m][r] - mn);
        m_run[m][r] = mn;
      }
#pragma unroll
    for (int m = 0; m < 2; ++m)
#pragma unroll
      for (int r = 0; r < 4; ++r) {
        p[m][0][r] = __expf(p[m][0][r] - m_run[m][r]);
        p[m][1][r] = __expf(p[m][1][r] - m_run[m][r]);
        float s = p[m][0][r] + p[m][1][r];
#pragma unroll
        for (int o = 1; o <= 8; o <<= 1) s += __shfl_xor(s, o);
        l_run[m][r] = l_run[m][r] * alpha[m][r] + s;
      }
#pragma unroll
    for (int m = 0; m < 2; ++m)
#pragma unroll
      for (int d8 = 0; d8 < 8; ++d8)
#pragma unroll
        for (int r = 0; r < 4; ++r) o_acc[m][d8][r] *= alpha[m][r];
#pragma unroll
    for (int m = 0; m < 2; ++m)
#pragma unroll
      for (int n = 0; n < 2; ++n)
#pragma unroll
        for (int r = 0; r < 4; ++r)
          P_lds[wave][m * 16 + (l4 << 2) + r][n * 16 + l15] = f2bf(p[m][n][r]);
    short8 pa[2];
#pragma unroll
    for (int m = 0; m < 2; ++m)
      pa[m] = *(const short8*)((const char*)&P_lds[wave][0][0] +
                               (m * 16 + l15) * 72 + (l4 << 4));
#pragma unroll
    for (int d8 = 0; d8 < 8; ++d8) {
      const short8 vb = *(const short8*)(
          vt + ((size_t)bh * 128 + d8 * 16 + l15) * 2048 + kbase + (l4 << 3));
      o_acc[0][d8] = MFMA16(pa[0], vb, o_acc[0][d8], 0, 0, 0);
      o_acc[1][d8] = MFMA16(pa[1], vb, o_acc[1][d8], 0, 0, 0);
    }
  }

  if (g == 0) {
#pragma unroll
    for (int m = 0; m < 2; ++m)
#pragma unroll
      for (int d8 = 0; d8 < 8; ++d8)
#pragma unroll
        for (int r = 0; r < 4; ++r) {
          const int row = brow + qrow_w + m * 16 + (l4 << 2) + r;
          Oh[(size_t)row * 512 + h * 128 + d8 * 16 + l15] =
              f2bf(o_acc[m][d8][r] / l_run[m][r]);
        }
  } else {
    const int slot = bh * 144 + blockIdx.x;
    unsigned short* po = pO + (size_t)slot * 64 * 128;
#pragma unroll
    for (int m = 0; m < 2; ++m)
#pragma unroll
      for (int d8 = 0; d8 < 8; ++d8)
#pragma unroll
        for (int r = 0; r < 4; ++r) {
          const int row = wave * 32 + m * 16 + (l4 << 2) + r;
          po[row * 128 + d8 * 16 + l15] = f2bf(o_acc[m][d8][r]);
        }
    if (l15 == 0) {
#pragma unroll
      for (int m = 0; m < 2; ++m)
#pragma unroll
        for (int r = 0; r < 4; ++r) {
          const int row = wave * 32 + m * 16 + (l4 << 2) + r;
          pml[((size_t)slot * 64 + row) * 2 + 0] = m_run[m][r];
          pml[((size_t)slot * 64 + row) * 2 + 1] = l_run[m][r];
        }
    }
  }
}

// Combine partials for qt >= 4. grid(28, 8), block 256.
__global__ __launch_bounds__(256)
void attn_combine(const unsigned short* __restrict__ pO,
                  const float* __restrict__ pml,
                  unsigned short* __restrict__ Oh) {
  const int bh = blockIdx.y;
  const int qt = 4 + blockIdx.x;
  const int g = qt >> 2;
  const int nch = g + 1;
  const int base = 2 * g * (g + 1) + (qt & 3) * (g + 1);
  const int slot0 = bh * 144 + base;
  const int brow = (bh >> 2) * 2048;
  const int h = bh & 3;
#pragma unroll
  for (int u = 0; u < 4; ++u) {
    const int unit = u * 256 + threadIdx.x;
    const int row = unit >> 4;
    const int c8 = (unit & 15) << 3;
    float M = -1e30f;
    for (int c = 0; c < nch; ++c)
      M = fmaxf(M, pml[((size_t)(slot0 + c) * 64 + row) * 2]);
    float L = 0.f;
    float acc[8] = {0.f, 0.f, 0.f, 0.f, 0.f, 0.f, 0.f, 0.f};
    for (int c = 0; c < nch; ++c) {
      const float mc = pml[((size_t)(slot0 + c) * 64 + row) * 2];
      const float lc = pml[((size_t)(slot0 + c) * 64 + row) * 2 + 1];
      const float w = __expf(mc - M);
      L += w * lc;
      const short8 ov =
          *(const short8*)(pO + ((size_t)(slot0 + c) * 64 + row) * 128 + c8);
#pragma unroll
      for (int e = 0; e < 8; ++e) acc[e] += w * bf2f((unsigned short)ov[e]);
    }
    const float inv = 1.f / L;
    short8 o;
#pragma unroll
    for (int e = 0; e < 8; ++e) o[e] = (short)f2bf(acc[e] * inv);
    *(short8*)(Oh + (size_t)(brow + qt * 64 + row) * 512 + h * 128 + c8) = o;
  }
}

// ---------------------------------------------------------------------------
extern "C" void kernel_launch(void* const* d_in, const int* in_sizes, int n_in,
                              void* d_out, int out_size, void* d_ws, size_t ws_size,
                              hipStream_t stream) {
  const float* Q  = (const float*)d_in[0];
  const float* K_ = (const float*)d_in[1];
  const float* V  = (const float*)d_in[2];
  const float* Wq = (const float*)d_in[3];
  const float* Wk = (const float*)d_in[4];
  const float* Wv = (const float*)d_in[5];
  const float* Wo = (const float*)d_in[6];
  float* out = (float*)d_out;

  // ws layout (bytes):
  //   0         : Wt   3 x [512][2048] bf16
  //   6291456   : WoT  [2048][512] bf16
  //   8388608   : qh/kh/vh/Oh 4 x [4096][512] bf16
  //   25165824  : vt   [8][128][2048] bf16
  //   29360128  : pO   [1152][64][128] bf16
  //   48234496  : pml  [1152][64][2] f32
  char* ws = (char*)d_ws;
  unsigned short* Wt  = (unsigned short*)ws;
  unsigned short* WoT = (unsigned short*)(ws + 6291456);
  unsigned short* qh  = (unsigned short*)(ws + 8388608);
  unsigned short* kh  = qh + 2097152;
  unsigned short* vh  = qh + 2 * 2097152;
  unsigned short* Oh  = qh + 3 * 2097152;
  unsigned short* vt  = (unsigned short*)(ws + 25165824);
  unsigned short* pO  = (unsigned short*)(ws + 29360128);
  float*          pml = (float*)(ws + 48234496);

  // weight prep
  wqsum_t<<<dim3(8, 32), 256, 0, stream>>>(Wq, Wt);
  transpose_w<<<dim3(8, 32), 256, 0, stream>>>(Wk, Wt + 1048576, 2048, 512);
  transpose_w<<<dim3(8, 32), 256, 0, stream>>>(Wv, Wt + 2097152, 2048, 512);
  transpose_w<<<dim3(32, 8), 256, 0, stream>>>(Wo, WoT, 512, 2048);

  // q/k/v projections: 3 z * 32 m-tiles * 4 n-tiles = 384 blocks
  gemm_bt<true, unsigned short><<<384, 256, 0, stream>>>(
      Q, K_, V, Wt, qh, /*K=*/2048, /*N=*/512, /*sB=*/1048576, /*sC=*/2097152);

  // V^T for the PV B-operand
  vtrans<<<dim3(32, 2, 8), 256, 0, stream>>>(vh, vt);

  // split-KV causal attention + combine
  attn_split<<<dim3(144, 8), 128, 0, stream>>>(qh, kh, vt, Oh, pO, pml);
  attn_combine<<<dim3(28, 8), 256, 0, stream>>>(pO, pml, Oh);

  // output projection: 32 m-tiles * 16 n-tiles = 512 blocks
  gemm_bt<false, float><<<512, 256, 0, stream>>>(
      Oh, Oh, Oh, WoT, out, /*K=*/512, /*N=*/2048, /*sB=*/0, /*sC=*/0);
}

// Round 5
// 157.685 us; speedup vs baseline: 1.4532x; 1.0701x over previous
//
#include <hip/hip_runtime.h>
#include <hip/hip_bf16.h>

typedef __attribute__((ext_vector_type(8))) short short8;
typedef __attribute__((ext_vector_type(4))) float f32x4;

#define MFMA16 __builtin_amdgcn_mfma_f32_16x16x32_bf16

__device__ inline unsigned short f2bf(float f) {
  __hip_bfloat16 h = __float2bfloat16(f);
  unsigned short u;
  __builtin_memcpy(&u, &h, 2);
  return u;
}

__device__ inline float bf2f(unsigned short u) {
  unsigned int x = ((unsigned int)u) << 16;
  float f;
  __builtin_memcpy(&f, &x, 4);
  return f;
}

__device__ inline void storeC(unsigned short* p, float v) { *p = f2bf(v); }
__device__ inline void storeC(float* p, float v) { *p = v; }

__device__ inline void gload16(const void* g, void* l) {
  __builtin_amdgcn_global_load_lds(
      (const __attribute__((address_space(1))) unsigned int*)g,
      (__attribute__((address_space(3))) unsigned int*)l,
      16, 0, 0);
}

// ---------------------------------------------------------------------------
// Weight prep: dst[n][d] = sum_g Wq[d][n + g*512], bf16 out. 512x2048 output.
__global__ __launch_bounds__(256)
void wqsum_t(const float* __restrict__ wq, unsigned short* __restrict__ dst) {
  __shared__ float t[64][65];
  const int n0 = blockIdx.x * 64, d0 = blockIdx.y * 64;
  const int tid = threadIdx.x;
#pragma unroll
  for (int it = 0; it < 16; ++it) {
    const int idx = it * 256 + tid;
    const int dd = idx >> 6, nn = idx & 63;
    const float* p = wq + (size_t)(d0 + dd) * 2048 + n0 + nn;
    t[dd][nn] = p[0] + p[512] + p[1024] + p[1536];
  }
  __syncthreads();
#pragma unroll
  for (int it = 0; it < 16; ++it) {
    const int idx = it * 256 + tid;
    const int nn = idx >> 6, dd = idx & 63;
    dst[(size_t)(n0 + nn) * 2048 + d0 + dd] = f2bf(t[dd][nn]);
  }
}

// Generic transpose+convert: dst[c][r] = src[r][c], src is R x C f32.
__global__ __launch_bounds__(256)
void transpose_w(const float* __restrict__ src, unsigned short* __restrict__ dst,
                 int R, int C) {
  __shared__ float t[64][65];
  const int c0 = blockIdx.x * 64, r0 = blockIdx.y * 64;
  const int tid = threadIdx.x;
#pragma unroll
  for (int it = 0; it < 16; ++it) {
    const int idx = it * 256 + tid;
    const int r = idx >> 6, c = idx & 63;
    t[r][c] = src[(size_t)(r0 + r) * C + c0 + c];
  }
  __syncthreads();
#pragma unroll
  for (int it = 0; it < 16; ++it) {
    const int idx = it * 256 + tid;
    const int rr = idx >> 6, cc = idx & 63;
    dst[(size_t)(c0 + rr) * R + r0 + cc] = f2bf(t[cc][rr]);
  }
}

// V transpose: vt[bh][d][s] = vh[brow+s][h*128+d]. grid(32, 2, 8).
__global__ __launch_bounds__(256)
void vtrans(const unsigned short* __restrict__ vh, unsigned short* __restrict__ vt) {
  __shared__ unsigned short t[64][72];
  const int s0 = blockIdx.x * 64;
  const int d0 = blockIdx.y * 64;
  const int bh = blockIdx.z;
  const int brow = (bh >> 2) * 2048;
  const int h = bh & 3;
  const int tid = threadIdx.x;
#pragma unroll
  for (int it = 0; it < 2; ++it) {
    const int idx = it * 256 + tid;
    const int s = idx >> 3;
    const int dd = (idx & 7) << 3;
    *(short8*)&t[s][dd] =
        *(const short8*)(vh + (size_t)(brow + s0 + s) * 512 + h * 128 + d0 + dd);
  }
  __syncthreads();
#pragma unroll
  for (int it = 0; it < 2; ++it) {
    const int idx = it * 256 + tid;
    const int dd = idx >> 3;
    const int ss = (idx & 7) << 3;
    short8 o;
#pragma unroll
    for (int e = 0; e < 8; ++e) o[e] = (short)t[ss + e][dd];
    *(short8*)(vt + ((size_t)bh * 128 + d0 + dd) * 2048 + s0 + ss) = o;
  }
}

// ---------------------------------------------------------------------------
// GEMM C[M,N] = A[M,K] * Bt[N,K]^T.  m97-structure: 128x128 tile, BK=64,
// 4 waves (2m x 2n, 64x64 each, acc 4x4), single-buffered 32KB LDS,
// stage -> bar -> compute -> bar.  T2 XOR swizzle on both operands.
// KS-way split-K: each block computes K/KS and writes a partial (CT=bf16)
// at C + (ks*3+z)*sC.  XCD-aware job swizzle, ks outermost / n innermost.
// 1D grid = KS * nz * 32 * (N/128); grid % 8 == 0.
template <bool AF32, typename CT, int KS>
__global__ __launch_bounds__(256)
void gemm_bt(const void* A0, const void* A1, const void* A2,
             const unsigned short* __restrict__ Bt, CT* __restrict__ C,
             int K, int N, size_t sB, size_t sC) {
  __shared__ unsigned short As[128 * 64];
  __shared__ unsigned short Bs[128 * 64];

  const int tid = threadIdx.x;
  const int lane = tid & 63;
  const int wv = tid >> 6;
  const int wm = (wv >> 1) << 6;
  const int wn = (wv & 1) << 6;
  const int l15 = lane & 15;
  const int l4 = lane >> 4;
  const int lsw = (l15 & 7) << 4;  // read-side swizzle (bytes)

  // XCD-aware bijective swizzle (nwg % 8 == 0), n-tiles innermost.
  const int nwg = gridDim.x;
  const int bid = blockIdx.x;
  const int job = (bid & 7) * (nwg >> 3) + (bid >> 3);
  const int ntile = N >> 7;
  const int per_ks = nwg / KS;
  const int ks = (KS > 1) ? (job / per_ks) : 0;
  const int jj = job - ks * per_ks;
  const int z = jj / (32 * ntile);
  const int rem = jj - z * 32 * ntile;
  const int m0 = (rem / ntile) << 7;
  const int n0 = (rem % ntile) << 7;
  const int kbeg = ks * (K / KS);
  const int kend = kbeg + K / KS;

  const void* Az = (z == 0) ? A0 : (z == 1) ? A1 : A2;
  const unsigned short* Ab = (const unsigned short*)Az;
  const float* Af = (const float*)Az;
  const unsigned short* Bz = Bt + sB * (size_t)z;

  const f32x4 zero = {0.f, 0.f, 0.f, 0.f};
  f32x4 acc[4][4];
#pragma unroll
  for (int i = 0; i < 4; ++i)
#pragma unroll
    for (int j = 0; j < 4; ++j) acc[i][j] = zero;

  const int srow = tid >> 3;                 // 0..31 (+32 per issue)
  const int scol = (tid & 7) << 3;           // element col, 0..56 step 8
  const int scolsw = scol ^ ((srow & 7) << 3);  // swizzled source col (elems)

  float4 ar[8];  // f32-A prefetch regs (AF32 path)

  auto issueB = [&](int k0) {
#pragma unroll
    for (int s = 0; s < 4; ++s) {
      const unsigned short* bsrc =
          Bz + (size_t)(n0 + srow + s * 32) * K + k0 + scolsw;
      gload16(bsrc, (char*)Bs + tid * 16 + s * 4096);
    }
  };
  auto issueA16 = [&](int k0) {
#pragma unroll
    for (int s = 0; s < 4; ++s) {
      const unsigned short* asrc =
          Ab + (size_t)(m0 + srow + s * 32) * K + k0 + scolsw;
      gload16(asrc, (char*)As + tid * 16 + s * 4096);
    }
  };
  auto loadA = [&](int k0) {
#pragma unroll
    for (int s = 0; s < 4; ++s) {
      const float* asrc = Af + (size_t)(m0 + srow + s * 32) * K + k0 + scol;
      ar[2 * s] = *(const float4*)(asrc);
      ar[2 * s + 1] = *(const float4*)(asrc + 4);
    }
  };
  auto writeA = [&]() {
#pragma unroll
    for (int s = 0; s < 4; ++s) {
      short8 o;
      o[0] = (short)f2bf(ar[2 * s].x); o[1] = (short)f2bf(ar[2 * s].y);
      o[2] = (short)f2bf(ar[2 * s].z); o[3] = (short)f2bf(ar[2 * s].w);
      o[4] = (short)f2bf(ar[2 * s + 1].x); o[5] = (short)f2bf(ar[2 * s + 1].y);
      o[6] = (short)f2bf(ar[2 * s + 1].z); o[7] = (short)f2bf(ar[2 * s + 1].w);
      *(short8*)((char*)As + (srow + s * 32) * 128 + scolsw * 2) = o;
    }
  };

  if constexpr (AF32) loadA(kbeg);

  for (int k0 = kbeg; k0 < kend; k0 += 64) {
    if constexpr (AF32) writeA(); else issueA16(k0);
    issueB(k0);
    if constexpr (AF32) {
      if (k0 + 64 < kend) loadA(k0 + 64);
    }
    __syncthreads();
#pragma unroll
    for (int kk = 0; kk < 2; ++kk) {
      const int kb = (kk * 64 + (l4 << 4)) ^ lsw;
      short8 a[4], b[4];
#pragma unroll
      for (int i = 0; i < 4; ++i)
        a[i] = *(const short8*)((const char*)As + (wm + i * 16 + l15) * 128 + kb);
#pragma unroll
      for (int j = 0; j < 4; ++j)
        b[j] = *(const short8*)((const char*)Bs + (wn + j * 16 + l15) * 128 + kb);
#pragma unroll
      for (int i = 0; i < 4; ++i)
#pragma unroll
        for (int j = 0; j < 4; ++j)
          acc[i][j] = MFMA16(a[i], b[j], acc[i][j], 0, 0, 0);
    }
    __syncthreads();
  }

  CT* Cz = C + sC * (size_t)(ks * 3 + z);
#pragma unroll
  for (int i = 0; i < 4; ++i) {
    const int row0 = m0 + wm + i * 16 + (l4 << 2);
#pragma unroll
    for (int j = 0; j < 4; ++j) {
      const int col = n0 + wn + j * 16 + l15;
#pragma unroll
      for (int r = 0; r < 4; ++r)
        storeC(&Cz[(size_t)(row0 + r) * N + col], acc[i][j][r]);
    }
  }
}

// Sum the two split-K bf16 partials into qh/kh/vh (contiguous 6291456 elems).
__global__ __launch_bounds__(256)
void qkv_combine(const unsigned short* __restrict__ pC,
                 unsigned short* __restrict__ dst) {
  const size_t HALF = 6291456;  // elems per ks-half (3 x 4096 x 512)
  size_t i = ((size_t)blockIdx.x * 256 + threadIdx.x) * 8;
  const size_t stride = (size_t)gridDim.x * 256 * 8;
  for (; i < HALF; i += stride) {
    const short8 a = *(const short8*)(pC + i);
    const short8 b = *(const short8*)(pC + HALF + i);
    short8 o;
#pragma unroll
    for (int e = 0; e < 8; ++e)
      o[e] = (short)f2bf(bf2f((unsigned short)a[e]) + bf2f((unsigned short)b[e]));
    *(short8*)(dst + i) = o;
  }
}

// ---------------------------------------------------------------------------
// Split-KV flash attention. Jobs: per bh, qt in 0..31 (64 q rows), KV chunks
// of 256. grid(144, 8), block = 128 (2 independent waves x 32 q rows).
__global__ __launch_bounds__(128)
void attn_split(const unsigned short* __restrict__ qh,
                const unsigned short* __restrict__ kh,
                const unsigned short* __restrict__ vt,
                unsigned short* __restrict__ Oh,
                unsigned short* __restrict__ pO,
                float* __restrict__ pml) {
  __shared__ unsigned short P_lds[2][32][36];
  const int tid = threadIdx.x;
  const int lane = tid & 63;
  const int wave = tid >> 6;
  const int l15 = lane & 15;
  const int l4 = lane >> 4;
  const int bh = blockIdx.y;
  const int brow = (bh >> 2) * 2048;
  const int h = bh & 3;

  int j = blockIdx.x, g = 0;
  while (j >= 2 * (g + 1) * (g + 2)) ++g;
  const int rem = j - 2 * g * (g + 1);
  const int r_ = rem / (g + 1);
  const int c_ = rem - r_ * (g + 1);
  const int qt = 4 * g + r_;
  const int k_begin = c_ << 8;
  const int k_end = (c_ == g) ? (qt + 1) * 64 : ((c_ + 1) << 8);
  const int qrow_w = qt * 64 + wave * 32;
  const float SCALE = 0.08838834764831845f;  // 1/sqrt(128)

  short8 qf[2][4];
#pragma unroll
  for (int m = 0; m < 2; ++m) {
    const unsigned short* qp =
        qh + (size_t)(brow + qrow_w + m * 16 + l15) * 512 + h * 128 + (l4 << 3);
#pragma unroll
    for (int kk = 0; kk < 4; ++kk) qf[m][kk] = *(const short8*)(qp + kk * 32);
  }

  const f32x4 zero = {0.f, 0.f, 0.f, 0.f};
  f32x4 o_acc[2][8];
#pragma unroll
  for (int m = 0; m < 2; ++m)
#pragma unroll
    for (int i = 0; i < 8; ++i) o_acc[m][i] = zero;
  float m_run[2][4], l_run[2][4];
#pragma unroll
  for (int m = 0; m < 2; ++m)
#pragma unroll
    for (int r = 0; r < 4; ++r) { m_run[m][r] = -1e30f; l_run[m][r] = 0.f; }

  const int nt = (k_end - k_begin) >> 5;
  for (int t = 0; t < nt; ++t) {
    const int kbase = k_begin + t * 32;
    f32x4 sa[2][2];
    sa[0][0] = zero; sa[0][1] = zero; sa[1][0] = zero; sa[1][1] = zero;
#pragma unroll
    for (int n = 0; n < 2; ++n) {
      short8 kf[4];
      const unsigned short* kp =
          kh + (size_t)(brow + kbase + n * 16 + l15) * 512 + h * 128 + (l4 << 3);
#pragma unroll
      for (int kk = 0; kk < 4; ++kk) kf[kk] = *(const short8*)(kp + kk * 32);
#pragma unroll
      for (int kk = 0; kk < 4; ++kk) {
        sa[0][n] = MFMA16(qf[0][kk], kf[kk], sa[0][n], 0, 0, 0);
        sa[1][n] = MFMA16(qf[1][kk], kf[kk], sa[1][n], 0, 0, 0);
      }
    }
    const bool need_mask = (kbase + 31 > qrow_w);
    float p[2][2][4];
#pragma unroll
    for (int m = 0; m < 2; ++m)
#pragma unroll
      for (int n = 0; n < 2; ++n)
#pragma unroll
        for (int r = 0; r < 4; ++r) {
          float v = sa[m][n][r] * SCALE;
          if (need_mask) {
            const int kc = kbase + n * 16 + l15;
            const int qr = qrow_w + m * 16 + (l4 << 2) + r;
            if (kc > qr) v = -1e30f;
          }
          p[m][n][r] = v;
        }
    float alpha[2][4];
#pragma unroll
    for (int m = 0; m < 2; ++m)
#pragma unroll
      for (int r = 0; r < 4; ++r) {
        float tmax = fmaxf(p[m][0][r], p[m][1][r]);
#pragma unroll
        for (int o = 1; o <= 8; o <<= 1) tmax = fmaxf(tmax, __shfl_xor(tmax, o));
        const float mn = fmaxf(m_run[m][r], tmax);
        alpha[m][r] = __expf(m_run[m][r] - mn);
        m_run[m][r] = mn;
      }
#pragma unroll
    for (int m = 0; m < 2; ++m)
#pragma unroll
      for (int r = 0; r < 4; ++r) {
        p[m][0][r] = __expf(p[m][0][r] - m_run[m][r]);
        p[m][1][r] = __expf(p[m][1][r] - m_run[m][r]);
        float s = p[m][0][r] + p[m][1][r];
#pragma unroll
        for (int o = 1; o <= 8; o <<= 1) s += __shfl_xor(s, o);
        l_run[m][r] = l_run[m][r] * alpha[m][r] + s;
      }
#pragma unroll
    for (int m = 0; m < 2; ++m)
#pragma unroll
      for (int d8 = 0; d8 < 8; ++d8)
#pragma unroll
        for (int r = 0; r < 4; ++r) o_acc[m][d8][r] *= alpha[m][r];
#pragma unroll
    for (int m = 0; m < 2; ++m)
#pragma unroll
      for (int n = 0; n < 2; ++n)
#pragma unroll
        for (int r = 0; r < 4; ++r)
          P_lds[wave][m * 16 + (l4 << 2) + r][n * 16 + l15] = f2bf(p[m][n][r]);
    short8 pa[2];
#pragma unroll
    for (int m = 0; m < 2; ++m)
      pa[m] = *(const short8*)((const char*)&P_lds[wave][0][0] +
                               (m * 16 + l15) * 72 + (l4 << 4));
#pragma unroll
    for (int d8 = 0; d8 < 8; ++d8) {
      const short8 vb = *(const short8*)(
          vt + ((size_t)bh * 128 + d8 * 16 + l15) * 2048 + kbase + (l4 << 3));
      o_acc[0][d8] = MFMA16(pa[0], vb, o_acc[0][d8], 0, 0, 0);
      o_acc[1][d8] = MFMA16(pa[1], vb, o_acc[1][d8], 0, 0, 0);
    }
  }

  if (g == 0) {
#pragma unroll
    for (int m = 0; m < 2; ++m)
#pragma unroll
      for (int d8 = 0; d8 < 8; ++d8)
#pragma unroll
        for (int r = 0; r < 4; ++r) {
          const int row = brow + qrow_w + m * 16 + (l4 << 2) + r;
          Oh[(size_t)row * 512 + h * 128 + d8 * 16 + l15] =
              f2bf(o_acc[m][d8][r] / l_run[m][r]);
        }
  } else {
    const int slot = bh * 144 + blockIdx.x;
    unsigned short* po = pO + (size_t)slot * 64 * 128;
#pragma unroll
    for (int m = 0; m < 2; ++m)
#pragma unroll
      for (int d8 = 0; d8 < 8; ++d8)
#pragma unroll
        for (int r = 0; r < 4; ++r) {
          const int row = wave * 32 + m * 16 + (l4 << 2) + r;
          po[row * 128 + d8 * 16 + l15] = f2bf(o_acc[m][d8][r]);
        }
    if (l15 == 0) {
#pragma unroll
      for (int m = 0; m < 2; ++m)
#pragma unroll
        for (int r = 0; r < 4; ++r) {
          const int row = wave * 32 + m * 16 + (l4 << 2) + r;
          pml[((size_t)slot * 64 + row) * 2 + 0] = m_run[m][r];
          pml[((size_t)slot * 64 + row) * 2 + 1] = l_run[m][r];
        }
    }
  }
}

// Combine partials for qt >= 4. grid(28, 8), block 256.
__global__ __launch_bounds__(256)
void attn_combine(const unsigned short* __restrict__ pO,
                  const float* __restrict__ pml,
                  unsigned short* __restrict__ Oh) {
  const int bh = blockIdx.y;
  const int qt = 4 + blockIdx.x;
  const int g = qt >> 2;
  const int nch = g + 1;
  const int base = 2 * g * (g + 1) + (qt & 3) * (g + 1);
  const int slot0 = bh * 144 + base;
  const int brow = (bh >> 2) * 2048;
  const int h = bh & 3;
#pragma unroll
  for (int u = 0; u < 4; ++u) {
    const int unit = u * 256 + threadIdx.x;
    const int row = unit >> 4;
    const int c8 = (unit & 15) << 3;
    float M = -1e30f;
    for (int c = 0; c < nch; ++c)
      M = fmaxf(M, pml[((size_t)(slot0 + c) * 64 + row) * 2]);
    float L = 0.f;
    float acc[8] = {0.f, 0.f, 0.f, 0.f, 0.f, 0.f, 0.f, 0.f};
    for (int c = 0; c < nch; ++c) {
      const float mc = pml[((size_t)(slot0 + c) * 64 + row) * 2];
      const float lc = pml[((size_t)(slot0 + c) * 64 + row) * 2 + 1];
      const float w = __expf(mc - M);
      L += w * lc;
      const short8 ov =
          *(const short8*)(pO + ((size_t)(slot0 + c) * 64 + row) * 128 + c8);
#pragma unroll
      for (int e = 0; e < 8; ++e) acc[e] += w * bf2f((unsigned short)ov[e]);
    }
    const float inv = 1.f / L;
    short8 o;
#pragma unroll
    for (int e = 0; e < 8; ++e) o[e] = (short)f2bf(acc[e] * inv);
    *(short8*)(Oh + (size_t)(brow + qt * 64 + row) * 512 + h * 128 + c8) = o;
  }
}

// ---------------------------------------------------------------------------
extern "C" void kernel_launch(void* const* d_in, const int* in_sizes, int n_in,
                              void* d_out, int out_size, void* d_ws, size_t ws_size,
                              hipStream_t stream) {
  const float* Q  = (const float*)d_in[0];
  const float* K_ = (const float*)d_in[1];
  const float* V  = (const float*)d_in[2];
  const float* Wq = (const float*)d_in[3];
  const float* Wk = (const float*)d_in[4];
  const float* Wv = (const float*)d_in[5];
  const float* Wo = (const float*)d_in[6];
  float* out = (float*)d_out;

  // ws layout (bytes):
  //   0         : Wt   3 x [512][2048] bf16
  //   6291456   : WoT  [2048][512] bf16
  //   8388608   : qh/kh/vh/Oh 4 x [4096][512] bf16
  //   25165824  : vt   [8][128][2048] bf16
  //   29360128  : pO   [1152][64][128] bf16
  //   48234496  : pml  [1152][64][2] f32
  //   pC (split-K bf16 partials, 2 x 6291456 elems = 25.2 MB) ALIASES
  //   [Oh, vt, pO-prefix] at offset 20971520 — lifetime ends at qkv_combine,
  //   before Oh/vt/pO are written. Total ws unchanged: 48824320 bytes.
  char* ws = (char*)d_ws;
  unsigned short* Wt  = (unsigned short*)ws;
  unsigned short* WoT = (unsigned short*)(ws + 6291456);
  unsigned short* qh  = (unsigned short*)(ws + 8388608);
  unsigned short* kh  = qh + 2097152;
  unsigned short* vh  = qh + 2 * 2097152;
  unsigned short* Oh  = qh + 3 * 2097152;
  unsigned short* vt  = (unsigned short*)(ws + 25165824);
  unsigned short* pO  = (unsigned short*)(ws + 29360128);
  float*          pml = (float*)(ws + 48234496);
  unsigned short* pC  = (unsigned short*)(ws + 20971520);

  // weight prep
  wqsum_t<<<dim3(8, 32), 256, 0, stream>>>(Wq, Wt);
  transpose_w<<<dim3(8, 32), 256, 0, stream>>>(Wk, Wt + 1048576, 2048, 512);
  transpose_w<<<dim3(8, 32), 256, 0, stream>>>(Wv, Wt + 2097152, 2048, 512);
  transpose_w<<<dim3(32, 8), 256, 0, stream>>>(Wo, WoT, 512, 2048);

  // q/k/v projections, split-K x2: 2 ks * 3 z * 32 m * 4 n = 768 blocks (3/CU)
  gemm_bt<true, unsigned short, 2><<<768, 256, 0, stream>>>(
      Q, K_, V, Wt, pC, /*K=*/2048, /*N=*/512, /*sB=*/1048576, /*sC=*/2097152);
  qkv_combine<<<1024, 256, 0, stream>>>(pC, qh);

  // V^T for the PV B-operand
  vtrans<<<dim3(32, 2, 8), 256, 0, stream>>>(vh, vt);

  // split-KV causal attention + combine
  attn_split<<<dim3(144, 8), 128, 0, stream>>>(qh, kh, vt, Oh, pO, pml);
  attn_combine<<<dim3(28, 8), 256, 0, stream>>>(pO, pml, Oh);

  // output projection: 32 m-tiles * 16 n-tiles = 512 blocks
  gemm_bt<false, float, 1><<<512, 256, 0, stream>>>(
      Oh, Oh, Oh, WoT, out, /*K=*/512, /*N=*/2048, /*sB=*/0, /*sC=*/0);
}